// Round 1
// baseline (562.350 us; speedup 1.0000x reference)
//
#include <hip/hip_runtime.h>

typedef unsigned short u16;
typedef unsigned int u32;
typedef unsigned char u8;
typedef long i64;
typedef float f4 __attribute__((ext_vector_type(4)));
typedef int i32x8 __attribute__((ext_vector_type(8)));

#define CDIM 768
#define NPROJ 5376
#define KFF 3840   // combined K for final gemm: 768 (attn) + 3072 (mlp)
#define NTOK 16384

// ---------------- fp8 e4m3 (OCP) conversion helpers, HW cvt when available
__device__ __forceinline__ u8 f2fp8(float f) {
#if __has_builtin(__builtin_amdgcn_cvt_pk_fp8_f32)
    return (u8)(__builtin_amdgcn_cvt_pk_fp8_f32(f, f, 0, false) & 0xff);
#else
    u32 u = __float_as_uint(f);
    u32 s = (u >> 24) & 0x80u;
    float a = fabsf(f);
    a = fminf(a, 448.f);
    if (a < 0.015625f) return (u8)(s | (u32)(a * 512.f + 0.5f));
    u32 b = __float_as_uint(a);
    b += 0x0007FFFFu + ((b >> 20) & 1u);
    u32 e = b >> 23, m = (b >> 20) & 7u;
    u32 code = ((e - 120u) << 3) | m;
    if (code > 0x7Eu) code = 0x7Eu;
    return (u8)(s | code);
#endif
}
__device__ __forceinline__ u32 pk4_fp8(float a, float b, float c, float d) {
#if __has_builtin(__builtin_amdgcn_cvt_pk_fp8_f32)
    u32 lo = (u32)__builtin_amdgcn_cvt_pk_fp8_f32(a, b, 0, false);
    return (u32)__builtin_amdgcn_cvt_pk_fp8_f32(c, d, lo, true);
#else
    return (u32)f2fp8(a) | ((u32)f2fp8(b) << 8) | ((u32)f2fp8(c) << 16) | ((u32)f2fp8(d) << 24);
#endif
}
__device__ __forceinline__ float fp8_to_f32(u32 v) {
#if __has_builtin(__builtin_amdgcn_cvt_f32_fp8)
    return __builtin_amdgcn_cvt_f32_fp8((int)v, 0);
#else
    u32 s = v >> 7, e = (v >> 3) & 15u, m = v & 7u;
    float mag = e ? __uint_as_float(((e + 120u) << 23) | (m << 20))
                  : (float)m * 0.001953125f;
    return s ? -mag : mag;
#endif
}

__device__ __forceinline__ float wsum64(float v) {
#pragma unroll
    for (int m = 32; m > 0; m >>= 1) v += __shfl_xor(v, m, 64);
    return v;
}
__device__ __forceinline__ void gl_lds16(const u8* g, u8* l) {
    __builtin_amdgcn_global_load_lds((__attribute__((address_space(1))) u32*)g,
                                     (__attribute__((address_space(3))) u32*)l,
                                     16, 0, 0);
}

// ---------------- transpose + fp32->fp8 cast: dst[c*dstride+doff+r] = src[r*Cc+c]
__global__ __launch_bounds__(256) void transpose_cast(const float* __restrict__ src,
                                                      u8* __restrict__ dst,
                                                      int R, int Cc, int dstride, int doff) {
    __shared__ float t[32][33];
    int c0 = blockIdx.x * 32, r0 = blockIdx.y * 32;
    int tx = threadIdx.x, ty = threadIdx.y;
#pragma unroll
    for (int i = 0; i < 32; i += 8) {
        int r = r0 + ty + i, c = c0 + tx;
        if (r < R && c < Cc) t[ty + i][tx] = src[(size_t)r * Cc + c];
    }
    __syncthreads();
#pragma unroll
    for (int i = 0; i < 32; i += 8) {
        int c = c0 + ty + i, r = r0 + tx;
        if (r < R && c < Cc) dst[(size_t)c * dstride + doff + r] = f2fp8(t[tx][ty + i]);
    }
}

// ---------------- LayerNorm over C=768, write fp8. 4 rows/block, one wave per row.
__global__ __launch_bounds__(256) void ln_rows(const float* __restrict__ x,
                                               const float* __restrict__ w,
                                               u8* __restrict__ xn) {
    int row = blockIdx.x * 4 + (threadIdx.x >> 6);
    int lane = threadIdx.x & 63;
    const f4* xr = (const f4*)(x + (size_t)row * CDIM);
    const f4* wr = (const f4*)w;
    f4 v[3];
    float s = 0.f, s2 = 0.f;
#pragma unroll
    for (int i = 0; i < 3; ++i) {
        v[i] = xr[lane + 64 * i];
#pragma unroll
        for (int j = 0; j < 4; ++j) { s += v[i][j]; s2 += v[i][j] * v[i][j]; }
    }
    s = wsum64(s); s2 = wsum64(s2);
    float mu = s * (1.f / 768.f);
    float var = s2 * (1.f / 768.f) - mu * mu;
    float rs = rsqrtf(var + 1e-5f);
    u32* xo = (u32*)(xn + (size_t)row * CDIM);
#pragma unroll
    for (int i = 0; i < 3; ++i) {
        f4 wv = wr[lane + 64 * i];
        xo[lane + 64 * i] = pk4_fp8((v[i][0] - mu) * rs * wv[0], (v[i][1] - mu) * rs * wv[1],
                                    (v[i][2] - mu) * rs * wv[2], (v[i][3] - mu) * rs * wv[3]);
    }
}

// ---------------- MX-fp8 MFMA GEMM (unit scales), A (MxK) fp8, B^T (NxK) fp8.
// 256x256 block tile, BK=128, 8-phase counted-vmcnt schedule (T2+T3+T4+T5):
//   512 threads = 8 waves (2x4), per-wave 128x64 output, acc 8x4 f32x4.
//   LDS 128 KiB = 2 dbuf x (A 32K + B 32K), 128B rows, 16B-chunk XOR swizzle
//   (phys chunk = logical ^ (row&7), same involution on stage-source and read).
//   Per K-tile (BK=128): 4 phases, each = {12 ds_read_b128 (one C-quadrant,
//   4mi x 2ni) || stage 2 half-tiles of t+1 (phases 0,1) -> barrier ->
//   lgkmcnt(0)+sched_barrier -> setprio(1) 8x mfma_scale 16x16x128 setprio(0)
//   -> barrier}. Single vmcnt(0) per K-tile at phase 3 (loads issued >=2
//   phases earlier stay in flight across the other 7 barriers).
// K-accumulation order per acc element identical to the 128^2 version ->
// bitwise-identical results.
// MODE 0: proj epilogue (+bqkv; cols<2304 -> fp8 qkv; else fast-gelu -> fp8 A2 ff)
// MODE 1: final epilogue (+bout+bmlp, out = x + gamma*acc, fp32)
template <int MODE>
__global__ __launch_bounds__(512, 2) void gemm_bt(
    const u8* __restrict__ A, const u8* __restrict__ B, int M, int N, int K,
    const float* __restrict__ bias0, const float* __restrict__ bias1,
    const float* __restrict__ xres, const float* __restrict__ gamma,
    u8* __restrict__ oqkv, u8* __restrict__ off, float* __restrict__ ofin) {
    __shared__ __align__(16) u8 lds[2][2][32768];   // [dbuf][A/B][256 rows x 128B]
    const int tid = threadIdx.x;
    const int wid = tid >> 6, lane = tid & 63;
    const int wm = wid >> 2, wn = wid & 3;          // 2x4 wave grid
    const int quad = lane >> 4, l16 = lane & 15;

    // bijective XCD swizzle (nwg % 8 == 0 for both call sites)
    const int nwg = (int)gridDim.x;
    int bid = (int)blockIdx.x;
    bid = (bid & 7) * (nwg >> 3) + (bid >> 3);
    const int nbx = N >> 8;
    const int m0 = (bid / nbx) << 8;
    const int n0 = (bid % nbx) << 8;
    const int NT = K >> 7;                          // K-tiles of 128

    f4 acc[8][4] = {};

    // staging: 8 global_load_lds per K-tile (A: 4 x 64 rows, B: 4 x 64 rows).
    // per call a wave covers 8 rows x 128B; lane l -> row +(l>>3), phys chunk
    // l&7, source logical chunk (l&7)^(row&7) with row&7 == l>>3.
    const int rl = lane >> 3;
    const int csw = ((lane & 7) ^ rl) * 16;
    const int srow = wid * 8 + rl;
    const u8* aptr[4]; const u8* bptr[4];
#pragma unroll
    for (int i = 0; i < 4; ++i) {
        aptr[i] = A + (size_t)(m0 + i * 64 + srow) * K + csw;
        bptr[i] = B + (size_t)(n0 + i * 64 + srow) * K + csw;
    }
    const int ldso = wid * 1024;                    // wid*8 rows * 128B

    // prologue: stage K-tile 0 into dbuf 0, full drain once
#pragma unroll
    for (int i = 0; i < 4; ++i) {
        gl_lds16(aptr[i], &lds[0][0][i * 8192 + ldso]);
        gl_lds16(bptr[i], &lds[0][1][i * 8192 + ldso]);
    }
    asm volatile("s_waitcnt vmcnt(0)" ::: "memory");
    __builtin_amdgcn_s_barrier();

    // read-side swizzle: logical chunks {2q, 2q+1} -> phys ^ (row&7)
    const int cb0 = ((2 * quad) ^ (l16 & 7)) * 16;
    const int cb1 = ((2 * quad + 1) ^ (l16 & 7)) * 16;

    for (int t = 0; t < NT; ++t) {
        const u8* Ab = lds[t & 1][0];
        const u8* Bb = lds[t & 1][1];
        u8* Aw = lds[(t & 1) ^ 1][0];
        u8* Bw = lds[(t & 1) ^ 1][1];
        const int pf = (t + 1 < NT);
        const size_t knext = (size_t)(t + 1) << 7;
#pragma unroll
        for (int p = 0; p < 4; ++p) {
            const int mib = (p & 1) * 4;            // quadrant: mi 0-3 / 4-7
            const int nib = (p >> 1) * 2;           //           ni 0-1 / 2-3
            // ---- issue frag ds_reads for this phase's 8 MFMAs
            i32x8 af[4]; i32x8 bf[2];
#pragma unroll
            for (int mi = 0; mi < 4; ++mi) {
                const u8* base = Ab + (wm * 128 + (mib + mi) * 16 + l16) * 128;
                uint4 lo = *(const uint4*)(base + cb0);
                uint4 hi = *(const uint4*)(base + cb1);
                af[mi][0] = lo.x; af[mi][1] = lo.y; af[mi][2] = lo.z; af[mi][3] = lo.w;
                af[mi][4] = hi.x; af[mi][5] = hi.y; af[mi][6] = hi.z; af[mi][7] = hi.w;
            }
#pragma unroll
            for (int ni = 0; ni < 2; ++ni) {
                const u8* base = Bb + (wn * 64 + (nib + ni) * 16 + l16) * 128;
                uint4 lo = *(const uint4*)(base + cb0);
                uint4 hi = *(const uint4*)(base + cb1);
                bf[ni][0] = lo.x; bf[ni][1] = lo.y; bf[ni][2] = lo.z; bf[ni][3] = lo.w;
                bf[ni][4] = hi.x; bf[ni][5] = hi.y; bf[ni][6] = hi.z; bf[ni][7] = hi.w;
            }
            // ---- stage next K-tile: 2 half-tiles (A+B) at phases 0 and 1
            if (p < 2 && pf) {
#pragma unroll
                for (int i = 2 * p; i < 2 * p + 2; ++i) {
                    gl_lds16(aptr[i] + knext, Aw + i * 8192 + ldso);
                    gl_lds16(bptr[i] + knext, Bw + i * 8192 + ldso);
                }
            }
            __builtin_amdgcn_sched_barrier(0);
            __builtin_amdgcn_s_barrier();
            asm volatile("s_waitcnt lgkmcnt(0)" ::: "memory");
            __builtin_amdgcn_sched_barrier(0);
            __builtin_amdgcn_s_setprio(1);
#pragma unroll
            for (int mi = 0; mi < 4; ++mi)
#pragma unroll
                for (int ni = 0; ni < 2; ++ni)
                    acc[mib + mi][nib + ni] = __builtin_amdgcn_mfma_scale_f32_16x16x128_f8f6f4(
                        af[mi], bf[ni], acc[mib + mi][nib + ni], 0, 0, 0, 127, 0, 127);
            __builtin_amdgcn_s_setprio(0);
            if (p == 3) asm volatile("s_waitcnt vmcnt(0)" ::: "memory");
            __builtin_amdgcn_s_barrier();
        }
    }

#pragma unroll
    for (int mi = 0; mi < 8; ++mi) {
#pragma unroll
        for (int ni = 0; ni < 4; ++ni) {
            const int col = n0 + wn * 64 + ni * 16 + l16;
            const int rowb = m0 + wm * 128 + mi * 16 + quad * 4;
            if (MODE == 0) {
                const float bc = bias0[col];
#pragma unroll
                for (int r = 0; r < 4; ++r) {
                    float vv = acc[mi][ni][r] + bc;
                    const int m = rowb + r;
                    if (col < 2304) {
                        oqkv[(size_t)m * 2304 + col] = f2fp8(vv);
                    } else {
                        // fast gelu: x*sigmoid(1.5957691216x + 0.0713548162x^3)
                        float u2 = vv * (-1.5957691216f) - 0.0713548162f * vv * vv * vv;
                        float g = vv / (1.f + __expf(u2));
                        off[(size_t)m * KFF + 768 + (col - 2304)] = f2fp8(g);
                    }
                }
            } else {
                const float bc = bias0[col] + bias1[col];
                const float gm = gamma[col];
#pragma unroll
                for (int r = 0; r < 4; ++r) {
                    const int m = rowb + r;
                    float vv = acc[mi][ni][r] + bc;
                    ofin[(size_t)m * CDIM + col] = xres[(size_t)m * CDIM + col] + gm * vv;
                }
            }
        }
    }
}

// ---------------- per-head LN of q and k (64-elem rows), in place on fp8 qkv buffer.
__global__ __launch_bounds__(256) void qk_ln(u8* __restrict__ qkv,
                                             const float* __restrict__ qw,
                                             const float* __restrict__ kw) {
    const size_t m = blockIdx.x;
    const int w = threadIdx.x >> 6, lane = threadIdx.x & 63;
#pragma unroll
    for (int it = 0; it < 6; ++it) {
        const int h = w + 4 * it;   // 0..23
        const int isq = (h < 12);
        const int he = isq ? h : h - 12;
        u8* p = qkv + m * 2304 + (isq ? 0 : 768) + he * 64 + lane;
        const float wt = (isq ? qw : kw)[lane];
        float v = fp8_to_f32(*p);
        float mu = wsum64(v) * (1.f / 64.f);
        float ex2 = wsum64(v * v) * (1.f / 64.f);
        float rs = rsqrtf(ex2 - mu * mu + 1e-5f);
        *p = f2fp8((v - mu) * rs * wt);
    }
}

// ---------------- fp8 MFMA axial attention: block = (b, line j, head he), 4 waves.
// phase 0 = row-j attention, phase 1 = column-j; register-accumulated, one
// fp8 write to A2[tok(b,i,j)]. S^T = K.Q^T (softmax per-lane + 2 quad
// shuffles), P->LDS (u32 packed), O = P.V with V^T built at load.
// All LDS tiles padded to 72B rows -> conflict-free 8B frag reads, no swizzle.
__global__ __launch_bounds__(256) void axial_attn_mfma(const u8* __restrict__ qkv,
                                                       u8* __restrict__ A2) {
    __shared__ __align__(16) u8 Qs[64 * 72];
    __shared__ __align__(16) u8 Ks[64 * 72];
    __shared__ __align__(16) u8 Vt[64 * 72];   // V^T[c][k]
    __shared__ __align__(16) u8 Ps[64 * 72];   // P[q][k]

    const int bx = blockIdx.x;
    const int he = bx % 12;
    const int j = (bx / 12) & 63;
    const int b = bx / (12 * 64);
    const int tid = threadIdx.x;
    const int w = tid >> 6, lane = tid & 63;
    const int l16 = lane & 15, quad = lane >> 4;
    const int qb = w * 16;

    f4 acc_o[4] = {};

    // staging thread mapping: row sr = tid>>2 (0..63), 16B segment sc = (tid&3)*16
    const int sr = tid >> 2;
    const int sc = (tid & 3) * 16;

    for (int phase = 0; phase < 2; ++phase) {
        const size_t tok = (phase == 0) ? (size_t)((b * 64 + j) * 64 + sr)
                                        : (size_t)((b * 64 + sr) * 64 + j);
        const u8* src = qkv + tok * 2304 + he * 64 + sc;
        {
            uint4 qv = *(const uint4*)(src);
            uint4 kv = *(const uint4*)(src + 768);
            *(uint4*)(Qs + sr * 72 + sc) = qv;
            *(uint4*)(Ks + sr * 72 + sc) = kv;
        }
        // V transposed: thread owns (k = sr, c in [sc, sc+16))
        {
            uint4 vv = *(const uint4*)(src + 1536);
            const u8* vb = (const u8*)&vv;
#pragma unroll
            for (int i = 0; i < 16; ++i) Vt[(sc + i) * 72 + sr] = vb[i];
        }
        __syncthreads();

        // ---- S^T tiles: D[m=k-idx][n=q], this wave's q-cols = qb..qb+15
        f4 st[4] = {};
#pragma unroll
        for (int kt = 0; kt < 2; ++kt) {
            const int boff = (kt * 4 + quad) * 8;
            const i64 bq = *(const i64*)(Qs + (qb + l16) * 72 + boff);
#pragma unroll
            for (int mt = 0; mt < 4; ++mt) {
                const i64 ak = *(const i64*)(Ks + (mt * 16 + l16) * 72 + boff);
                st[mt] = __builtin_amdgcn_mfma_f32_16x16x32_fp8_fp8(ak, bq, st[mt], 0, 0, 0);
            }
        }

        // ---- softmax over k (= m axis): per-lane 16 values + cross-quad shuffles
        float sv[16];
        float mx = -1e30f;
#pragma unroll
        for (int mt = 0; mt < 4; ++mt)
#pragma unroll
            for (int r = 0; r < 4; ++r) {
                const float s = st[mt][r] * 0.125f;
                sv[mt * 4 + r] = s;
                mx = fmaxf(mx, s);
            }
        mx = fmaxf(mx, __shfl_xor(mx, 16, 64));
        mx = fmaxf(mx, __shfl_xor(mx, 32, 64));
        float sm = 0.f;
#pragma unroll
        for (int i = 0; i < 16; ++i) { sv[i] = __expf(sv[i] - mx); sm += sv[i]; }
        sm += __shfl_xor(sm, 16, 64);
        sm += __shfl_xor(sm, 32, 64);
        const float inv = 1.f / sm;

        // ---- write P[q][k] (transpose out of C-layout), packed u32 stores
#pragma unroll
        for (int mt = 0; mt < 4; ++mt) {
            const int kbase = mt * 16 + quad * 4;
            *(u32*)(Ps + (qb + l16) * 72 + kbase) =
                pk4_fp8(sv[mt * 4] * inv, sv[mt * 4 + 1] * inv,
                        sv[mt * 4 + 2] * inv, sv[mt * 4 + 3] * inv);
        }
        __syncthreads();

        // ---- O += P.V : m-tile = this wave's q rows, n-tiles over c
#pragma unroll
        for (int kt = 0; kt < 2; ++kt) {
            const int boff = (kt * 4 + quad) * 8;
            const i64 ap = *(const i64*)(Ps + (qb + l16) * 72 + boff);
#pragma unroll
            for (int nt = 0; nt < 4; ++nt) {
                const i64 bv = *(const i64*)(Vt + (nt * 16 + l16) * 72 + boff);
                acc_o[nt] = __builtin_amdgcn_mfma_f32_16x16x32_fp8_fp8(ap, bv, acc_o[nt], 0, 0, 0);
            }
        }
        __syncthreads();   // protect tiles before next phase reload
    }

    // ---- store: q = qb + quad*4 + r, c = nt*16 + l16
#pragma unroll
    for (int nt = 0; nt < 4; ++nt)
#pragma unroll
        for (int r = 0; r < 4; ++r) {
            const int q = qb + quad * 4 + r;
            const int c = nt * 16 + l16;
            A2[((size_t)((b * 64 + q) * 64 + j)) * KFF + he * 64 + c] = f2fp8(acc_o[nt][r]);
        }
}

extern "C" void kernel_launch(void* const* d_in, const int* in_sizes, int n_in,
                              void* d_out, int out_size, void* d_ws, size_t ws_size,
                              hipStream_t stream) {
    const float* x = (const float*)d_in[0];
    const float* normw = (const float*)d_in[1];
    const float* Wqkv = (const float*)d_in[2];
    const float* bqkv = (const float*)d_in[3];
    const float* qnw = (const float*)d_in[4];
    const float* knw = (const float*)d_in[5];
    const float* Wout = (const float*)d_in[6];
    const float* bout = (const float*)d_in[7];
    const float* Wmlp = (const float*)d_in[8];
    const float* bmlp = (const float*)d_in[9];
    const float* gamma = (const float*)d_in[10];
    float* out = (float*)d_out;

    char* ws = (char*)d_ws;
    u8* xn = (u8*)ws;    ws += (size_t)NTOK * CDIM;
    u8* WqkvT = (u8*)ws; ws += (size_t)NPROJ * CDIM;
    u8* BT2 = (u8*)ws;   ws += (size_t)CDIM * KFF;
    u8* qkv = (u8*)ws;   ws += (size_t)NTOK * 2304;
    u8* A2 = (u8*)ws;    ws += (size_t)NTOK * KFF;

    // weights -> B^T fp8
    transpose_cast<<<dim3(NPROJ / 32, CDIM / 32), dim3(32, 8), 0, stream>>>(Wqkv, WqkvT, CDIM, NPROJ, CDIM, 0);
    transpose_cast<<<dim3(CDIM / 32, CDIM / 32), dim3(32, 8), 0, stream>>>(Wout, BT2, CDIM, CDIM, KFF, 0);
    transpose_cast<<<dim3(CDIM / 32, 3072 / 32), dim3(32, 8), 0, stream>>>(Wmlp, BT2, 3072, CDIM, KFF, 768);
    // LN(x) -> fp8
    ln_rows<<<NTOK / 4, 256, 0, stream>>>(x, normw, xn);
    // proj GEMM: q,k,v -> qkv buffer; gelu(ff) -> A2[:, 768:3840]
    gemm_bt<0><<<dim3((NPROJ / 256) * (NTOK / 256)), 512, 0, stream>>>(
        xn, WqkvT, NTOK, NPROJ, CDIM, bqkv, nullptr, nullptr, nullptr, qkv, A2, nullptr);
    // per-head LN of q,k in place
    qk_ln<<<NTOK, 256, 0, stream>>>(qkv, qnw, knw);
    // both axial attentions -> A2[:, 0:768]
    axial_attn_mfma<<<3072, 256, 0, stream>>>(qkv, A2);
    // final fused GEMM: out = x + gamma * (A2 @ [WoutT|WmlpT] + bout + bmlp)
    gemm_bt<1><<<dim3((CDIM / 256) * (NTOK / 256)), 512, 0, stream>>>(
        A2, BT2, NTOK, CDIM, KFF, bout, bmlp, x, gamma, nullptr, nullptr, out);
}

// Round 2
// 444.490 us; speedup vs baseline: 1.2652x; 1.2652x over previous
//
#include <hip/hip_runtime.h>

typedef unsigned short u16;
typedef unsigned int u32;
typedef unsigned char u8;
typedef long i64;
typedef float f4 __attribute__((ext_vector_type(4)));
typedef int i32x8 __attribute__((ext_vector_type(8)));

#define CDIM 768
#define NPROJ 5376
#define KFF 3840   // combined K for final gemm: 768 (attn) + 3072 (mlp)
#define NTOK 16384

// ---------------- fp8 e4m3 (OCP) conversion helpers, HW cvt when available
__device__ __forceinline__ u8 f2fp8(float f) {
#if __has_builtin(__builtin_amdgcn_cvt_pk_fp8_f32)
    return (u8)(__builtin_amdgcn_cvt_pk_fp8_f32(f, f, 0, false) & 0xff);
#else
    u32 u = __float_as_uint(f);
    u32 s = (u >> 24) & 0x80u;
    float a = fabsf(f);
    a = fminf(a, 448.f);
    if (a < 0.015625f) return (u8)(s | (u32)(a * 512.f + 0.5f));
    u32 b = __float_as_uint(a);
    b += 0x0007FFFFu + ((b >> 20) & 1u);
    u32 e = b >> 23, m = (b >> 20) & 7u;
    u32 code = ((e - 120u) << 3) | m;
    if (code > 0x7Eu) code = 0x7Eu;
    return (u8)(s | code);
#endif
}
__device__ __forceinline__ u32 pk4_fp8(float a, float b, float c, float d) {
#if __has_builtin(__builtin_amdgcn_cvt_pk_fp8_f32)
    u32 lo = (u32)__builtin_amdgcn_cvt_pk_fp8_f32(a, b, 0, false);
    return (u32)__builtin_amdgcn_cvt_pk_fp8_f32(c, d, lo, true);
#else
    return (u32)f2fp8(a) | ((u32)f2fp8(b) << 8) | ((u32)f2fp8(c) << 16) | ((u32)f2fp8(d) << 24);
#endif
}
__device__ __forceinline__ float fp8_to_f32(u32 v) {
#if __has_builtin(__builtin_amdgcn_cvt_f32_fp8)
    return __builtin_amdgcn_cvt_f32_fp8((int)v, 0);
#else
    u32 s = v >> 7, e = (v >> 3) & 15u, m = v & 7u;
    float mag = e ? __uint_as_float(((e + 120u) << 23) | (m << 20))
                  : (float)m * 0.001953125f;
    return s ? -mag : mag;
#endif
}

__device__ __forceinline__ float wsum64(float v) {
#pragma unroll
    for (int m = 32; m > 0; m >>= 1) v += __shfl_xor(v, m, 64);
    return v;
}
__device__ __forceinline__ void gl_lds16(const u8* g, u8* l) {
    __builtin_amdgcn_global_load_lds((__attribute__((address_space(1))) u32*)g,
                                     (__attribute__((address_space(3))) u32*)l,
                                     16, 0, 0);
}

// ---------------- transpose + fp32->fp8 cast: dst[c*dstride+doff+r] = src[r*Cc+c]
__global__ __launch_bounds__(256) void transpose_cast(const float* __restrict__ src,
                                                      u8* __restrict__ dst,
                                                      int R, int Cc, int dstride, int doff) {
    __shared__ float t[32][33];
    int c0 = blockIdx.x * 32, r0 = blockIdx.y * 32;
    int tx = threadIdx.x, ty = threadIdx.y;
#pragma unroll
    for (int i = 0; i < 32; i += 8) {
        int r = r0 + ty + i, c = c0 + tx;
        if (r < R && c < Cc) t[ty + i][tx] = src[(size_t)r * Cc + c];
    }
    __syncthreads();
#pragma unroll
    for (int i = 0; i < 32; i += 8) {
        int c = c0 + ty + i, r = r0 + tx;
        if (r < R && c < Cc) dst[(size_t)c * dstride + doff + r] = f2fp8(t[tx][ty + i]);
    }
}

// ---------------- LayerNorm over C=768, write fp8. 4 rows/block, one wave per row.
__global__ __launch_bounds__(256) void ln_rows(const float* __restrict__ x,
                                               const float* __restrict__ w,
                                               u8* __restrict__ xn) {
    int row = blockIdx.x * 4 + (threadIdx.x >> 6);
    int lane = threadIdx.x & 63;
    const f4* xr = (const f4*)(x + (size_t)row * CDIM);
    const f4* wr = (const f4*)w;
    f4 v[3];
    float s = 0.f, s2 = 0.f;
#pragma unroll
    for (int i = 0; i < 3; ++i) {
        v[i] = xr[lane + 64 * i];
#pragma unroll
        for (int j = 0; j < 4; ++j) { s += v[i][j]; s2 += v[i][j] * v[i][j]; }
    }
    s = wsum64(s); s2 = wsum64(s2);
    float mu = s * (1.f / 768.f);
    float var = s2 * (1.f / 768.f) - mu * mu;
    float rs = rsqrtf(var + 1e-5f);
    u32* xo = (u32*)(xn + (size_t)row * CDIM);
#pragma unroll
    for (int i = 0; i < 3; ++i) {
        f4 wv = wr[lane + 64 * i];
        xo[lane + 64 * i] = pk4_fp8((v[i][0] - mu) * rs * wv[0], (v[i][1] - mu) * rs * wv[1],
                                    (v[i][2] - mu) * rs * wv[2], (v[i][3] - mu) * rs * wv[3]);
    }
}

// ---------------- MX-fp8 MFMA GEMM (unit scales), A (MxK) fp8, B^T (NxK) fp8.
// 128x128 block tile, BK=128, 128B LDS rows with 16B-granule XOR swizzle
// (phys chunk = logical ^ (row&7) -> conflict-free b128 reads, round-5-proven).
// 4 waves (2x2); per K-tile each wave: 16 ds_read_b128 pairs -> 16
// mfma_scale_f32_16x16x128_f8f6f4 (K=128 in one instruction, 2x fp8 rate).
// ROUND-2 CHANGE (only change vs round-0): double-buffered LDS 2-phase
// schedule (catalog T3-minimum). Next K-tile's global_load_lds is issued
// BEFORE computing the current tile; ONE __syncthreads per K-tile (its
// vmcnt(0) drain lands ~1100 cyc after issue -> HBM latency hidden), vs
// round-0's stage -> drain -> compute which exposed full latency per tile.
// Frag pattern / accumulation order / epilogue identical to round-0 ->
// bitwise-identical results. LDS 64 KiB -> still 2 blocks/CU.
// MODE 0: proj epilogue (+bqkv; cols<2304 -> fp8 qkv; else fast-gelu -> fp8 A2 ff)
// MODE 1: final epilogue (+bout+bmlp, out = x + gamma*acc, fp32)
template <int MODE>
__global__ __launch_bounds__(256) void gemm_bt(
    const u8* __restrict__ A, const u8* __restrict__ B, int M, int N, int K,
    const float* __restrict__ bias0, const float* __restrict__ bias1,
    const float* __restrict__ xres, const float* __restrict__ gamma,
    u8* __restrict__ oqkv, u8* __restrict__ off, float* __restrict__ ofin) {
    __shared__ __align__(16) u8 As[2][128 * 128];
    __shared__ __align__(16) u8 Bs[2][128 * 128];
    const int tid = threadIdx.x;
    const int wid = tid >> 6, lane = tid & 63;
    const int wm = wid >> 1, wn = wid & 1;
    const int quad = lane >> 4, l16 = lane & 15;
    const int m0 = blockIdx.y * 128, n0 = blockIdx.x * 128;
    const int NT = K >> 7;

    f4 acc[4][4] = {};

    // staging: each glds16 call = 8 rows x 128B. 4 A-calls + 4 B-calls per wave.
    // lane l: row-in-call = l>>3, phys 16B chunk = l&7; source logical chunk =
    // (l&7) ^ (row&7) with row&7 = l>>3.
    const int rl = lane >> 3;
    const int csw = ((lane & 7) ^ rl) * 16;           // swizzled source byte offset
    const u8* aptr[4]; const u8* bptr[4];
    int ro[4];
#pragma unroll
    for (int jj = 0; jj < 4; ++jj) {
        const int r0 = wid * 32 + jj * 8;
        aptr[jj] = A + (size_t)(m0 + r0 + rl) * K + csw;
        bptr[jj] = B + (size_t)(n0 + r0 + rl) * K + csw;
        ro[jj] = r0 * 128;
    }
    const int swl = l16 & 7;                          // read-side swizzle (16B-chunk units)
    const int cb0 = ((2 * quad) ^ swl) * 16;
    const int cb1 = ((2 * quad + 1) ^ swl) * 16;

    // prologue: stage K-tile 0 into buffer 0 (drained by the syncthreads)
#pragma unroll
    for (int jj = 0; jj < 4; ++jj) {
        gl_lds16(aptr[jj], &As[0][ro[jj]]);
        gl_lds16(bptr[jj], &Bs[0][ro[jj]]);
    }
    __syncthreads();

    for (int t = 0; t < NT; ++t) {
        const int cur = t & 1, nxt = cur ^ 1;
        // ---- issue next K-tile staging FIRST (lands during this tile's compute)
        if (t + 1 < NT) {
            const size_t ko = (size_t)(t + 1) << 7;
#pragma unroll
            for (int jj = 0; jj < 4; ++jj) {
                gl_lds16(aptr[jj] + ko, &As[nxt][ro[jj]]);
                gl_lds16(bptr[jj] + ko, &Bs[nxt][ro[jj]]);
            }
        }
        // ---- per-lane A/B frag: 32 k-bytes at k0 = quad*32 -> logical chunks 2q,2q+1
        i32x8 af[4], bfv[4];
#pragma unroll
        for (int mi = 0; mi < 4; ++mi) {
            const u8* base = As[cur] + (wm * 64 + mi * 16 + l16) * 128;
            uint4 lo = *(const uint4*)(base + cb0);
            uint4 hi = *(const uint4*)(base + cb1);
            af[mi][0] = lo.x; af[mi][1] = lo.y; af[mi][2] = lo.z; af[mi][3] = lo.w;
            af[mi][4] = hi.x; af[mi][5] = hi.y; af[mi][6] = hi.z; af[mi][7] = hi.w;
        }
#pragma unroll
        for (int ni = 0; ni < 4; ++ni) {
            const u8* base = Bs[cur] + (wn * 64 + ni * 16 + l16) * 128;
            uint4 lo = *(const uint4*)(base + cb0);
            uint4 hi = *(const uint4*)(base + cb1);
            bfv[ni][0] = lo.x; bfv[ni][1] = lo.y; bfv[ni][2] = lo.z; bfv[ni][3] = lo.w;
            bfv[ni][4] = hi.x; bfv[ni][5] = hi.y; bfv[ni][6] = hi.z; bfv[ni][7] = hi.w;
        }
#pragma unroll
        for (int mi = 0; mi < 4; ++mi)
#pragma unroll
            for (int ni = 0; ni < 4; ++ni)
                acc[mi][ni] = __builtin_amdgcn_mfma_scale_f32_16x16x128_f8f6f4(
                    af[mi], bfv[ni], acc[mi][ni], 0, 0, 0, 127, 0, 127);
        // one barrier per K-tile: drains vmcnt(0) (next tile resident) and
        // guards this tile's buffer against iteration t+1's staging writes.
        __syncthreads();
    }

#pragma unroll
    for (int mi = 0; mi < 4; ++mi) {
#pragma unroll
        for (int ni = 0; ni < 4; ++ni) {
            const int col = n0 + wn * 64 + ni * 16 + l16;
            const int rowb = m0 + wm * 64 + mi * 16 + quad * 4;
            if (MODE == 0) {
                const float bc = bias0[col];
#pragma unroll
                for (int r = 0; r < 4; ++r) {
                    float vv = acc[mi][ni][r] + bc;
                    const int m = rowb + r;
                    if (col < 2304) {
                        oqkv[(size_t)m * 2304 + col] = f2fp8(vv);
                    } else {
                        // fast gelu: x*sigmoid(1.5957691216x + 0.0713548162x^3)
                        float u2 = vv * (-1.5957691216f) - 0.0713548162f * vv * vv * vv;
                        float g = vv / (1.f + __expf(u2));
                        off[(size_t)m * KFF + 768 + (col - 2304)] = f2fp8(g);
                    }
                }
            } else {
                const float bc = bias0[col] + bias1[col];
                const float gm = gamma[col];
#pragma unroll
                for (int r = 0; r < 4; ++r) {
                    const int m = rowb + r;
                    float vv = acc[mi][ni][r] + bc;
                    ofin[(size_t)m * CDIM + col] = xres[(size_t)m * CDIM + col] + gm * vv;
                }
            }
        }
    }
}

// ---------------- per-head LN of q and k (64-elem rows), in place on fp8 qkv buffer.
__global__ __launch_bounds__(256) void qk_ln(u8* __restrict__ qkv,
                                             const float* __restrict__ qw,
                                             const float* __restrict__ kw) {
    const size_t m = blockIdx.x;
    const int w = threadIdx.x >> 6, lane = threadIdx.x & 63;
#pragma unroll
    for (int it = 0; it < 6; ++it) {
        const int h = w + 4 * it;   // 0..23
        const int isq = (h < 12);
        const int he = isq ? h : h - 12;
        u8* p = qkv + m * 2304 + (isq ? 0 : 768) + he * 64 + lane;
        const float wt = (isq ? qw : kw)[lane];
        float v = fp8_to_f32(*p);
        float mu = wsum64(v) * (1.f / 64.f);
        float ex2 = wsum64(v * v) * (1.f / 64.f);
        float rs = rsqrtf(ex2 - mu * mu + 1e-5f);
        *p = f2fp8((v - mu) * rs * wt);
    }
}

// ---------------- fp8 MFMA axial attention: block = (b, line j, head he), 4 waves.
// phase 0 = row-j attention, phase 1 = column-j; register-accumulated, one
// fp8 write to A2[tok(b,i,j)]. S^T = K.Q^T (softmax per-lane + 2 quad
// shuffles), P->LDS (u32 packed), O = P.V with V^T built at load.
// All LDS tiles padded to 72B rows -> conflict-free 8B frag reads, no swizzle.
__global__ __launch_bounds__(256) void axial_attn_mfma(const u8* __restrict__ qkv,
                                                       u8* __restrict__ A2) {
    __shared__ __align__(16) u8 Qs[64 * 72];
    __shared__ __align__(16) u8 Ks[64 * 72];
    __shared__ __align__(16) u8 Vt[64 * 72];   // V^T[c][k]
    __shared__ __align__(16) u8 Ps[64 * 72];   // P[q][k]

    const int bx = blockIdx.x;
    const int he = bx % 12;
    const int j = (bx / 12) & 63;
    const int b = bx / (12 * 64);
    const int tid = threadIdx.x;
    const int w = tid >> 6, lane = tid & 63;
    const int l16 = lane & 15, quad = lane >> 4;
    const int qb = w * 16;

    f4 acc_o[4] = {};

    // staging thread mapping: row sr = tid>>2 (0..63), 16B segment sc = (tid&3)*16
    const int sr = tid >> 2;
    const int sc = (tid & 3) * 16;

    for (int phase = 0; phase < 2; ++phase) {
        const size_t tok = (phase == 0) ? (size_t)((b * 64 + j) * 64 + sr)
                                        : (size_t)((b * 64 + sr) * 64 + j);
        const u8* src = qkv + tok * 2304 + he * 64 + sc;
        {
            uint4 qv = *(const uint4*)(src);
            uint4 kv = *(const uint4*)(src + 768);
            *(uint4*)(Qs + sr * 72 + sc) = qv;
            *(uint4*)(Ks + sr * 72 + sc) = kv;
        }
        // V transposed: thread owns (k = sr, c in [sc, sc+16))
        {
            uint4 vv = *(const uint4*)(src + 1536);
            const u8* vb = (const u8*)&vv;
#pragma unroll
            for (int i = 0; i < 16; ++i) Vt[(sc + i) * 72 + sr] = vb[i];
        }
        __syncthreads();

        // ---- S^T tiles: D[m=k-idx][n=q], this wave's q-cols = qb..qb+15
        f4 st[4] = {};
#pragma unroll
        for (int kt = 0; kt < 2; ++kt) {
            const int boff = (kt * 4 + quad) * 8;
            const i64 bq = *(const i64*)(Qs + (qb + l16) * 72 + boff);
#pragma unroll
            for (int mt = 0; mt < 4; ++mt) {
                const i64 ak = *(const i64*)(Ks + (mt * 16 + l16) * 72 + boff);
                st[mt] = __builtin_amdgcn_mfma_f32_16x16x32_fp8_fp8(ak, bq, st[mt], 0, 0, 0);
            }
        }

        // ---- softmax over k (= m axis): per-lane 16 values + cross-quad shuffles
        float sv[16];
        float mx = -1e30f;
#pragma unroll
        for (int mt = 0; mt < 4; ++mt)
#pragma unroll
            for (int r = 0; r < 4; ++r) {
                const float s = st[mt][r] * 0.125f;
                sv[mt * 4 + r] = s;
                mx = fmaxf(mx, s);
            }
        mx = fmaxf(mx, __shfl_xor(mx, 16, 64));
        mx = fmaxf(mx, __shfl_xor(mx, 32, 64));
        float sm = 0.f;
#pragma unroll
        for (int i = 0; i < 16; ++i) { sv[i] = __expf(sv[i] - mx); sm += sv[i]; }
        sm += __shfl_xor(sm, 16, 64);
        sm += __shfl_xor(sm, 32, 64);
        const float inv = 1.f / sm;

        // ---- write P[q][k] (transpose out of C-layout), packed u32 stores
#pragma unroll
        for (int mt = 0; mt < 4; ++mt) {
            const int kbase = mt * 16 + quad * 4;
            *(u32*)(Ps + (qb + l16) * 72 + kbase) =
                pk4_fp8(sv[mt * 4] * inv, sv[mt * 4 + 1] * inv,
                        sv[mt * 4 + 2] * inv, sv[mt * 4 + 3] * inv);
        }
        __syncthreads();

        // ---- O += P.V : m-tile = this wave's q rows, n-tiles over c
#pragma unroll
        for (int kt = 0; kt < 2; ++kt) {
            const int boff = (kt * 4 + quad) * 8;
            const i64 ap = *(const i64*)(Ps + (qb + l16) * 72 + boff);
#pragma unroll
            for (int nt = 0; nt < 4; ++nt) {
                const i64 bv = *(const i64*)(Vt + (nt * 16 + l16) * 72 + boff);
                acc_o[nt] = __builtin_amdgcn_mfma_f32_16x16x32_fp8_fp8(ap, bv, acc_o[nt], 0, 0, 0);
            }
        }
        __syncthreads();   // protect tiles before next phase reload
    }

    // ---- store: q = qb + quad*4 + r, c = nt*16 + l16
#pragma unroll
    for (int nt = 0; nt < 4; ++nt)
#pragma unroll
        for (int r = 0; r < 4; ++r) {
            const int q = qb + quad * 4 + r;
            const int c = nt * 16 + l16;
            A2[((size_t)((b * 64 + q) * 64 + j)) * KFF + he * 64 + c] = f2fp8(acc_o[nt][r]);
        }
}

extern "C" void kernel_launch(void* const* d_in, const int* in_sizes, int n_in,
                              void* d_out, int out_size, void* d_ws, size_t ws_size,
                              hipStream_t stream) {
    const float* x = (const float*)d_in[0];
    const float* normw = (const float*)d_in[1];
    const float* Wqkv = (const float*)d_in[2];
    const float* bqkv = (const float*)d_in[3];
    const float* qnw = (const float*)d_in[4];
    const float* knw = (const float*)d_in[5];
    const float* Wout = (const float*)d_in[6];
    const float* bout = (const float*)d_in[7];
    const float* Wmlp = (const float*)d_in[8];
    const float* bmlp = (const float*)d_in[9];
    const float* gamma = (const float*)d_in[10];
    float* out = (float*)d_out;

    char* ws = (char*)d_ws;
    u8* xn = (u8*)ws;    ws += (size_t)NTOK * CDIM;
    u8* WqkvT = (u8*)ws; ws += (size_t)NPROJ * CDIM;
    u8* BT2 = (u8*)ws;   ws += (size_t)CDIM * KFF;
    u8* qkv = (u8*)ws;   ws += (size_t)NTOK * 2304;
    u8* A2 = (u8*)ws;    ws += (size_t)NTOK * KFF;

    // weights -> B^T fp8
    transpose_cast<<<dim3(NPROJ / 32, CDIM / 32), dim3(32, 8), 0, stream>>>(Wqkv, WqkvT, CDIM, NPROJ, CDIM, 0);
    transpose_cast<<<dim3(CDIM / 32, CDIM / 32), dim3(32, 8), 0, stream>>>(Wout, BT2, CDIM, CDIM, KFF, 0);
    transpose_cast<<<dim3(CDIM / 32, 3072 / 32), dim3(32, 8), 0, stream>>>(Wmlp, BT2, 3072, CDIM, KFF, 768);
    // LN(x) -> fp8
    ln_rows<<<NTOK / 4, 256, 0, stream>>>(x, normw, xn);
    // proj GEMM: q,k,v -> qkv buffer; gelu(ff) -> A2[:, 768:3840]
    gemm_bt<0><<<dim3(NPROJ / 128, NTOK / 128), 256, 0, stream>>>(
        xn, WqkvT, NTOK, NPROJ, CDIM, bqkv, nullptr, nullptr, nullptr, qkv, A2, nullptr);
    // per-head LN of q,k in place
    qk_ln<<<NTOK, 256, 0, stream>>>(qkv, qnw, knw);
    // both axial attentions -> A2[:, 0:768]
    axial_attn_mfma<<<3072, 256, 0, stream>>>(qkv, A2);
    // final fused GEMM: out = x + gamma * (A2 @ [WoutT|WmlpT] + bout + bmlp)
    gemm_bt<1><<<dim3(CDIM / 128, NTOK / 128), 256, 0, stream>>>(
        A2, BT2, NTOK, CDIM, KFF, bout, bmlp, x, gamma, nullptr, nullptr, out);
}

// Round 4
// 434.237 us; speedup vs baseline: 1.2950x; 1.0236x over previous
//
#include <hip/hip_runtime.h>

typedef unsigned short u16;
typedef unsigned int u32;
typedef unsigned char u8;
typedef long i64;
typedef float f4 __attribute__((ext_vector_type(4)));
typedef float f16v __attribute__((ext_vector_type(16)));
typedef int i32x8 __attribute__((ext_vector_type(8)));

#define CDIM 768
#define NPROJ 5376
#define KFF 3840   // combined K for final gemm: 768 (attn) + 3072 (mlp)
#define NTOK 16384

// ---------------- fp8 e4m3 (OCP) conversion helpers, HW cvt when available
__device__ __forceinline__ u8 f2fp8(float f) {
#if __has_builtin(__builtin_amdgcn_cvt_pk_fp8_f32)
    return (u8)(__builtin_amdgcn_cvt_pk_fp8_f32(f, f, 0, false) & 0xff);
#else
    u32 u = __float_as_uint(f);
    u32 s = (u >> 24) & 0x80u;
    float a = fabsf(f);
    a = fminf(a, 448.f);
    if (a < 0.015625f) return (u8)(s | (u32)(a * 512.f + 0.5f));
    u32 b = __float_as_uint(a);
    b += 0x0007FFFFu + ((b >> 20) & 1u);
    u32 e = b >> 23, m = (b >> 20) & 7u;
    u32 code = ((e - 120u) << 3) | m;
    if (code > 0x7Eu) code = 0x7Eu;
    return (u8)(s | code);
#endif
}
__device__ __forceinline__ u32 pk4_fp8(float a, float b, float c, float d) {
#if __has_builtin(__builtin_amdgcn_cvt_pk_fp8_f32)
    u32 lo = (u32)__builtin_amdgcn_cvt_pk_fp8_f32(a, b, 0, false);
    return (u32)__builtin_amdgcn_cvt_pk_fp8_f32(c, d, lo, true);
#else
    return (u32)f2fp8(a) | ((u32)f2fp8(b) << 8) | ((u32)f2fp8(c) << 16) | ((u32)f2fp8(d) << 24);
#endif
}
__device__ __forceinline__ float fp8_to_f32(u32 v) {
#if __has_builtin(__builtin_amdgcn_cvt_f32_fp8)
    return __builtin_amdgcn_cvt_f32_fp8((int)v, 0);
#else
    u32 s = v >> 7, e = (v >> 3) & 15u, m = v & 7u;
    float mag = e ? __uint_as_float(((e + 120u) << 23) | (m << 20))
                  : (float)m * 0.001953125f;
    return s ? -mag : mag;
#endif
}

__device__ __forceinline__ float wsum64(float v) {
#pragma unroll
    for (int m = 32; m > 0; m >>= 1) v += __shfl_xor(v, m, 64);
    return v;
}
__device__ __forceinline__ void gl_lds16(const u8* g, u8* l) {
    __builtin_amdgcn_global_load_lds((__attribute__((address_space(1))) u32*)g,
                                     (__attribute__((address_space(3))) u32*)l,
                                     16, 0, 0);
}

// ---------------- transpose + fp32->fp8 cast: dst[c*dstride+doff+r] = src[r*Cc+c]
__global__ __launch_bounds__(256) void transpose_cast(const float* __restrict__ src,
                                                      u8* __restrict__ dst,
                                                      int R, int Cc, int dstride, int doff) {
    __shared__ float t[32][33];
    int c0 = blockIdx.x * 32, r0 = blockIdx.y * 32;
    int tx = threadIdx.x, ty = threadIdx.y;
#pragma unroll
    for (int i = 0; i < 32; i += 8) {
        int r = r0 + ty + i, c = c0 + tx;
        if (r < R && c < Cc) t[ty + i][tx] = src[(size_t)r * Cc + c];
    }
    __syncthreads();
#pragma unroll
    for (int i = 0; i < 32; i += 8) {
        int c = c0 + ty + i, r = r0 + tx;
        if (r < R && c < Cc) dst[(size_t)c * dstride + doff + r] = f2fp8(t[tx][ty + i]);
    }
}

// ---------------- LayerNorm over C=768, write fp8. 4 rows/block, one wave per row.
__global__ __launch_bounds__(256) void ln_rows(const float* __restrict__ x,
                                               const float* __restrict__ w,
                                               u8* __restrict__ xn) {
    int row = blockIdx.x * 4 + (threadIdx.x >> 6);
    int lane = threadIdx.x & 63;
    const f4* xr = (const f4*)(x + (size_t)row * CDIM);
    const f4* wr = (const f4*)w;
    f4 v[3];
    float s = 0.f, s2 = 0.f;
#pragma unroll
    for (int i = 0; i < 3; ++i) {
        v[i] = xr[lane + 64 * i];
#pragma unroll
        for (int j = 0; j < 4; ++j) { s += v[i][j]; s2 += v[i][j] * v[i][j]; }
    }
    s = wsum64(s); s2 = wsum64(s2);
    float mu = s * (1.f / 768.f);
    float var = s2 * (1.f / 768.f) - mu * mu;
    float rs = rsqrtf(var + 1e-5f);
    u32* xo = (u32*)(xn + (size_t)row * CDIM);
#pragma unroll
    for (int i = 0; i < 3; ++i) {
        f4 wv = wr[lane + 64 * i];
        xo[lane + 64 * i] = pk4_fp8((v[i][0] - mu) * rs * wv[0], (v[i][1] - mu) * rs * wv[1],
                                    (v[i][2] - mu) * rs * wv[2], (v[i][3] - mu) * rs * wv[3]);
    }
}

// ---------------- MX-fp8 MFMA GEMM (unit scales), A (MxK) fp8, B^T (NxK) fp8.
// ROUND-4 = round-3 resubmitted (round-3 bench was an infra failure, no data).
// 128x128 block tile, BK=64, mfma_scale_f32_32x32x64_f8f6f4.
//   Per-wave 64x64 output = 2x2 of 32x32, acc 4x f32x16.
//   LDS: 2 dbuf x (A 8K + B 8K) = 32 KiB TOTAL (= round-0 footprint ->
//   occupancy limits identical to round-0), with round-2's prefetch-
//   before-compute 2-phase overlap retained (round-2's regression tracked
//   its 64K LDS / lost TLP, not the overlap itself).
//   Layout: 64B LDS rows; phys 16B chunk = logical ^ ((row>>1)&3).
//   Staging dest linear (wave-uniform base + lane*16), source pre-swizzled:
//   lane l -> row l>>2, logical chunk (l&3)^((l>>3)&3). Frag ds_read_b128:
//   each 8-lane group covers all 32 banks exactly once -> conflict-free.
//   A-operand: lane holds A[row=lane&31][k=32*(lane>>5)..+31] (dword asc).
//   C/D: col=lane&31, row=(reg&3)+8*(reg>>2)+4*(lane>>5)  [guide-verified].
// MODE 0: proj epilogue (+bqkv; cols<2304 -> fp8 qkv; else fast-gelu -> fp8 A2 ff)
// MODE 1: final epilogue (+bout+bmlp, out = x + gamma*acc, fp32)
template <int MODE>
__global__ __launch_bounds__(256) void gemm_bt(
    const u8* __restrict__ A, const u8* __restrict__ B, int M, int N, int K,
    const float* __restrict__ bias0, const float* __restrict__ bias1,
    const float* __restrict__ xres, const float* __restrict__ gamma,
    u8* __restrict__ oqkv, u8* __restrict__ off, float* __restrict__ ofin) {
    __shared__ __align__(16) u8 As[2][128 * 64];
    __shared__ __align__(16) u8 Bs[2][128 * 64];
    const int tid = threadIdx.x;
    const int wid = tid >> 6, lane = tid & 63;
    const int wm = wid >> 1, wn = wid & 1;
    const int l31 = lane & 31, h = lane >> 5;
    const int m0 = blockIdx.y * 128, n0 = blockIdx.x * 128;
    const int NT = K >> 6;                            // K-tiles of 64

    f16v acc[2][2] = {};

    // ---- staging: 16 gl_lds16 calls per K-tile (A rows 0..127 in 8 calls of
    // 16 rows, B likewise); wave w does A calls {w, w+4}, B calls {w, w+4}.
    // lane l: row-in-call = l>>2, phys chunk = l&3,
    // source logical chunk = (l&3) ^ ((l>>3)&3)  (since (16*call)>>1 % 4 == 0).
    const int srl = lane >> 2;                        // row in call
    const int csw = ((lane & 3) ^ ((lane >> 3) & 3)) * 16;
    const u8* aptr[2]; const u8* bptr[2];
    int ro[2];
#pragma unroll
    for (int j = 0; j < 2; ++j) {
        const int r0 = (wid + 4 * j) * 16;
        aptr[j] = A + (size_t)(m0 + r0 + srl) * K + csw;
        bptr[j] = B + (size_t)(n0 + r0 + srl) * K + csw;
        ro[j] = r0 * 64;
    }

    // ---- frag read offsets: row r = wm*64+mi*32+l31, s=(r>>1)&3=(l31>>1)&3;
    // logical chunks {2h, 2h+1} -> phys ^ s.
    const int s = (l31 >> 1) & 3;
    const int fo0 = ((2 * h) ^ s) * 16;
    const int fo1 = ((2 * h + 1) ^ s) * 16;

    // prologue: stage K-tile 0 into buffer 0 (drained by the syncthreads)
#pragma unroll
    for (int j = 0; j < 2; ++j) {
        gl_lds16(aptr[j], &As[0][ro[j]]);
        gl_lds16(bptr[j], &Bs[0][ro[j]]);
    }
    __syncthreads();

    for (int t = 0; t < NT; ++t) {
        const int cur = t & 1, nxt = cur ^ 1;
        // ---- issue next K-tile staging FIRST (lands during this tile's compute)
        if (t + 1 < NT) {
            const size_t ko = (size_t)(t + 1) << 6;
#pragma unroll
            for (int j = 0; j < 2; ++j) {
                gl_lds16(aptr[j] + ko, &As[nxt][ro[j]]);
                gl_lds16(bptr[j] + ko, &Bs[nxt][ro[j]]);
            }
        }
        // ---- per-lane A/B frags: 32 k-bytes each
        i32x8 af[2], bf[2];
#pragma unroll
        for (int mi = 0; mi < 2; ++mi) {
            const u8* base = As[cur] + (wm * 64 + mi * 32 + l31) * 64;
            uint4 lo = *(const uint4*)(base + fo0);
            uint4 hi = *(const uint4*)(base + fo1);
            af[mi][0] = lo.x; af[mi][1] = lo.y; af[mi][2] = lo.z; af[mi][3] = lo.w;
            af[mi][4] = hi.x; af[mi][5] = hi.y; af[mi][6] = hi.z; af[mi][7] = hi.w;
        }
#pragma unroll
        for (int ni = 0; ni < 2; ++ni) {
            const u8* base = Bs[cur] + (wn * 64 + ni * 32 + l31) * 64;
            uint4 lo = *(const uint4*)(base + fo0);
            uint4 hi = *(const uint4*)(base + fo1);
            bf[ni][0] = lo.x; bf[ni][1] = lo.y; bf[ni][2] = lo.z; bf[ni][3] = lo.w;
            bf[ni][4] = hi.x; bf[ni][5] = hi.y; bf[ni][6] = hi.z; bf[ni][7] = hi.w;
        }
#pragma unroll
        for (int mi = 0; mi < 2; ++mi)
#pragma unroll
            for (int ni = 0; ni < 2; ++ni)
                acc[mi][ni] = __builtin_amdgcn_mfma_scale_f32_32x32x64_f8f6f4(
                    af[mi], bf[ni], acc[mi][ni], 0, 0, 0, 127, 0, 127);
        // one barrier per K-tile: drains vmcnt(0) (next tile resident) and
        // guards this tile's buffer against iteration t+1's staging writes.
        __syncthreads();
    }

    // ---- epilogue: col = n0+wn*64+ni*32+l31; row = m0+wm*64+mi*32+4h+(reg&3)+8*(reg>>2)
#pragma unroll
    for (int mi = 0; mi < 2; ++mi) {
#pragma unroll
        for (int ni = 0; ni < 2; ++ni) {
            const int col = n0 + wn * 64 + ni * 32 + l31;
            const int rowb = m0 + wm * 64 + mi * 32 + 4 * h;
            if (MODE == 0) {
                const float bc = bias0[col];
#pragma unroll
                for (int reg = 0; reg < 16; ++reg) {
                    const int m = rowb + (reg & 3) + 8 * (reg >> 2);
                    float vv = acc[mi][ni][reg] + bc;
                    if (col < 2304) {
                        oqkv[(size_t)m * 2304 + col] = f2fp8(vv);
                    } else {
                        // fast gelu: x*sigmoid(1.5957691216x + 0.0713548162x^3)
                        float u2 = vv * (-1.5957691216f) - 0.0713548162f * vv * vv * vv;
                        float g = vv / (1.f + __expf(u2));
                        off[(size_t)m * KFF + 768 + (col - 2304)] = f2fp8(g);
                    }
                }
            } else {
                const float bc = bias0[col] + bias1[col];
                const float gm = gamma[col];
#pragma unroll
                for (int reg = 0; reg < 16; ++reg) {
                    const int m = rowb + (reg & 3) + 8 * (reg >> 2);
                    float vv = acc[mi][ni][reg] + bc;
                    ofin[(size_t)m * CDIM + col] = xres[(size_t)m * CDIM + col] + gm * vv;
                }
            }
        }
    }
}

// ---------------- per-head LN of q and k (64-elem rows), in place on fp8 qkv buffer.
__global__ __launch_bounds__(256) void qk_ln(u8* __restrict__ qkv,
                                             const float* __restrict__ qw,
                                             const float* __restrict__ kw) {
    const size_t m = blockIdx.x;
    const int w = threadIdx.x >> 6, lane = threadIdx.x & 63;
#pragma unroll
    for (int it = 0; it < 6; ++it) {
        const int h = w + 4 * it;   // 0..23
        const int isq = (h < 12);
        const int he = isq ? h : h - 12;
        u8* p = qkv + m * 2304 + (isq ? 0 : 768) + he * 64 + lane;
        const float wt = (isq ? qw : kw)[lane];
        float v = fp8_to_f32(*p);
        float mu = wsum64(v) * (1.f / 64.f);
        float ex2 = wsum64(v * v) * (1.f / 64.f);
        float rs = rsqrtf(ex2 - mu * mu + 1e-5f);
        *p = f2fp8((v - mu) * rs * wt);
    }
}

// ---------------- fp8 MFMA axial attention: block = (b, line j, head he), 4 waves.
// phase 0 = row-j attention, phase 1 = column-j; register-accumulated, one
// fp8 write to A2[tok(b,i,j)]. S^T = K.Q^T (softmax per-lane + 2 quad
// shuffles), P->LDS (u32 packed), O = P.V with V^T built at load.
// All LDS tiles padded to 72B rows -> conflict-free 8B frag reads, no swizzle.
__global__ __launch_bounds__(256) void axial_attn_mfma(const u8* __restrict__ qkv,
                                                       u8* __restrict__ A2) {
    __shared__ __align__(16) u8 Qs[64 * 72];
    __shared__ __align__(16) u8 Ks[64 * 72];
    __shared__ __align__(16) u8 Vt[64 * 72];   // V^T[c][k]
    __shared__ __align__(16) u8 Ps[64 * 72];   // P[q][k]

    const int bx = blockIdx.x;
    const int he = bx % 12;
    const int j = (bx / 12) & 63;
    const int b = bx / (12 * 64);
    const int tid = threadIdx.x;
    const int w = tid >> 6, lane = tid & 63;
    const int l16 = lane & 15, quad = lane >> 4;
    const int qb = w * 16;

    f4 acc_o[4] = {};

    // staging thread mapping: row sr = tid>>2 (0..63), 16B segment sc = (tid&3)*16
    const int sr = tid >> 2;
    const int sc = (tid & 3) * 16;

    for (int phase = 0; phase < 2; ++phase) {
        const size_t tok = (phase == 0) ? (size_t)((b * 64 + j) * 64 + sr)
                                        : (size_t)((b * 64 + sr) * 64 + j);
        const u8* src = qkv + tok * 2304 + he * 64 + sc;
        {
            uint4 qv = *(const uint4*)(src);
            uint4 kv = *(const uint4*)(src + 768);
            *(uint4*)(Qs + sr * 72 + sc) = qv;
            *(uint4*)(Ks + sr * 72 + sc) = kv;
        }
        // V transposed: thread owns (k = sr, c in [sc, sc+16))
        {
            uint4 vv = *(const uint4*)(src + 1536);
            const u8* vb = (const u8*)&vv;
#pragma unroll
            for (int i = 0; i < 16; ++i) Vt[(sc + i) * 72 + sr] = vb[i];
        }
        __syncthreads();

        // ---- S^T tiles: D[m=k-idx][n=q], this wave's q-cols = qb..qb+15
        f4 st[4] = {};
#pragma unroll
        for (int kt = 0; kt < 2; ++kt) {
            const int boff = (kt * 4 + quad) * 8;
            const i64 bq = *(const i64*)(Qs + (qb + l16) * 72 + boff);
#pragma unroll
            for (int mt = 0; mt < 4; ++mt) {
                const i64 ak = *(const i64*)(Ks + (mt * 16 + l16) * 72 + boff);
                st[mt] = __builtin_amdgcn_mfma_f32_16x16x32_fp8_fp8(ak, bq, st[mt], 0, 0, 0);
            }
        }

        // ---- softmax over k (= m axis): per-lane 16 values + cross-quad shuffles
        float sv[16];
        float mx = -1e30f;
#pragma unroll
        for (int mt = 0; mt < 4; ++mt)
#pragma unroll
            for (int r = 0; r < 4; ++r) {
                const float s = st[mt][r] * 0.125f;
                sv[mt * 4 + r] = s;
                mx = fmaxf(mx, s);
            }
        mx = fmaxf(mx, __shfl_xor(mx, 16, 64));
        mx = fmaxf(mx, __shfl_xor(mx, 32, 64));
        float sm = 0.f;
#pragma unroll
        for (int i = 0; i < 16; ++i) { sv[i] = __expf(sv[i] - mx); sm += sv[i]; }
        sm += __shfl_xor(sm, 16, 64);
        sm += __shfl_xor(sm, 32, 64);
        const float inv = 1.f / sm;

        // ---- write P[q][k] (transpose out of C-layout), packed u32 stores
#pragma unroll
        for (int mt = 0; mt < 4; ++mt) {
            const int kbase = mt * 16 + quad * 4;
            *(u32*)(Ps + (qb + l16) * 72 + kbase) =
                pk4_fp8(sv[mt * 4] * inv, sv[mt * 4 + 1] * inv,
                        sv[mt * 4 + 2] * inv, sv[mt * 4 + 3] * inv);
        }
        __syncthreads();

        // ---- O += P.V : m-tile = this wave's q rows, n-tiles over c
#pragma unroll
        for (int kt = 0; kt < 2; ++kt) {
            const int boff = (kt * 4 + quad) * 8;
            const i64 ap = *(const i64*)(Ps + (qb + l16) * 72 + boff);
#pragma unroll
            for (int nt = 0; nt < 4; ++nt) {
                const i64 bv = *(const i64*)(Vt + (nt * 16 + l16) * 72 + boff);
                acc_o[nt] = __builtin_amdgcn_mfma_f32_16x16x32_fp8_fp8(ap, bv, acc_o[nt], 0, 0, 0);
            }
        }
        __syncthreads();   // protect tiles before next phase reload
    }

    // ---- store: q = qb + quad*4 + r, c = nt*16 + l16
#pragma unroll
    for (int nt = 0; nt < 4; ++nt)
#pragma unroll
        for (int r = 0; r < 4; ++r) {
            const int q = qb + quad * 4 + r;
            const int c = nt * 16 + l16;
            A2[((size_t)((b * 64 + q) * 64 + j)) * KFF + he * 64 + c] = f2fp8(acc_o[nt][r]);
        }
}

extern "C" void kernel_launch(void* const* d_in, const int* in_sizes, int n_in,
                              void* d_out, int out_size, void* d_ws, size_t ws_size,
                              hipStream_t stream) {
    const float* x = (const float*)d_in[0];
    const float* normw = (const float*)d_in[1];
    const float* Wqkv = (const float*)d_in[2];
    const float* bqkv = (const float*)d_in[3];
    const float* qnw = (const float*)d_in[4];
    const float* knw = (const float*)d_in[5];
    const float* Wout = (const float*)d_in[6];
    const float* bout = (const float*)d_in[7];
    const float* Wmlp = (const float*)d_in[8];
    const float* bmlp = (const float*)d_in[9];
    const float* gamma = (const float*)d_in[10];
    float* out = (float*)d_out;

    char* ws = (char*)d_ws;
    u8* xn = (u8*)ws;    ws += (size_t)NTOK * CDIM;
    u8* WqkvT = (u8*)ws; ws += (size_t)NPROJ * CDIM;
    u8* BT2 = (u8*)ws;   ws += (size_t)CDIM * KFF;
    u8* qkv = (u8*)ws;   ws += (size_t)NTOK * 2304;
    u8* A2 = (u8*)ws;    ws += (size_t)NTOK * KFF;

    // weights -> B^T fp8
    transpose_cast<<<dim3(NPROJ / 32, CDIM / 32), dim3(32, 8), 0, stream>>>(Wqkv, WqkvT, CDIM, NPROJ, CDIM, 0);
    transpose_cast<<<dim3(CDIM / 32, CDIM / 32), dim3(32, 8), 0, stream>>>(Wout, BT2, CDIM, CDIM, KFF, 0);
    transpose_cast<<<dim3(CDIM / 32, 3072 / 32), dim3(32, 8), 0, stream>>>(Wmlp, BT2, 3072, CDIM, KFF, 768);
    // LN(x) -> fp8
    ln_rows<<<NTOK / 4, 256, 0, stream>>>(x, normw, xn);
    // proj GEMM: q,k,v -> qkv buffer; gelu(ff) -> A2[:, 768:3840]
    gemm_bt<0><<<dim3(NPROJ / 128, NTOK / 128), 256, 0, stream>>>(
        xn, WqkvT, NTOK, NPROJ, CDIM, bqkv, nullptr, nullptr, nullptr, qkv, A2, nullptr);
    // per-head LN of q,k in place
    qk_ln<<<NTOK, 256, 0, stream>>>(qkv, qnw, knw);
    // both axial attentions -> A2[:, 0:768]
    axial_attn_mfma<<<3072, 256, 0, stream>>>(qkv, A2);
    // final fused GEMM: out = x + gamma * (A2 @ [WoutT|WmlpT] + bout + bmlp)
    gemm_bt<1><<<dim3(CDIM / 128, NTOK / 128), 256, 0, stream>>>(
        A2, BT2, NTOK, CDIM, KFF, bout, bmlp, x, gamma, nullptr, nullptr, out);
}

// Round 5
// 367.943 us; speedup vs baseline: 1.5284x; 1.1802x over previous
//
#include <hip/hip_runtime.h>

typedef unsigned short u16;
typedef unsigned int u32;
typedef unsigned char u8;
typedef long i64;
typedef float f4 __attribute__((ext_vector_type(4)));
typedef int i32x8 __attribute__((ext_vector_type(8)));

#define CDIM 768
#define NPROJ 5376
#define KFF 3840   // combined K for final gemm: 768 (attn) + 3072 (mlp)
#define NTOK 16384

// ---------------- fp8 e4m3 (OCP) conversion helpers, HW cvt when available
__device__ __forceinline__ u8 f2fp8(float f) {
#if __has_builtin(__builtin_amdgcn_cvt_pk_fp8_f32)
    return (u8)(__builtin_amdgcn_cvt_pk_fp8_f32(f, f, 0, false) & 0xff);
#else
    u32 u = __float_as_uint(f);
    u32 s = (u >> 24) & 0x80u;
    float a = fabsf(f);
    a = fminf(a, 448.f);
    if (a < 0.015625f) return (u8)(s | (u32)(a * 512.f + 0.5f));
    u32 b = __float_as_uint(a);
    b += 0x0007FFFFu + ((b >> 20) & 1u);
    u32 e = b >> 23, m = (b >> 20) & 7u;
    u32 code = ((e - 120u) << 3) | m;
    if (code > 0x7Eu) code = 0x7Eu;
    return (u8)(s | code);
#endif
}
__device__ __forceinline__ u32 pk4_fp8(float a, float b, float c, float d) {
#if __has_builtin(__builtin_amdgcn_cvt_pk_fp8_f32)
    u32 lo = (u32)__builtin_amdgcn_cvt_pk_fp8_f32(a, b, 0, false);
    return (u32)__builtin_amdgcn_cvt_pk_fp8_f32(c, d, lo, true);
#else
    return (u32)f2fp8(a) | ((u32)f2fp8(b) << 8) | ((u32)f2fp8(c) << 16) | ((u32)f2fp8(d) << 24);
#endif
}
__device__ __forceinline__ float fp8_to_f32(u32 v) {
#if __has_builtin(__builtin_amdgcn_cvt_f32_fp8)
    return __builtin_amdgcn_cvt_f32_fp8((int)v, 0);
#else
    u32 s = v >> 7, e = (v >> 3) & 15u, m = v & 7u;
    float mag = e ? __uint_as_float(((e + 120u) << 23) | (m << 20))
                  : (float)m * 0.001953125f;
    return s ? -mag : mag;
#endif
}

__device__ __forceinline__ float wsum64(float v) {
#pragma unroll
    for (int m = 32; m > 0; m >>= 1) v += __shfl_xor(v, m, 64);
    return v;
}
__device__ __forceinline__ void gl_lds16(const u8* g, u8* l) {
    __builtin_amdgcn_global_load_lds((__attribute__((address_space(1))) u32*)g,
                                     (__attribute__((address_space(3))) u32*)l,
                                     16, 0, 0);
}

// ---------------- fused prep: 3 weight transpose+casts and the x LayerNorm,
// all independent, in ONE launch (removes 3 launch gaps).
// blocks [0,4032): Wqkv -> WqkvT ; [4032,4608): Wout -> BT2[:,0:768]
// blocks [4608,6912): Wmlp -> BT2[:,768:3840] ; [6912,11008): ln_rows
__global__ __launch_bounds__(256) void prep_fused(
    const float* __restrict__ Wqkv, u8* __restrict__ WqkvT,
    const float* __restrict__ Wout, const float* __restrict__ Wmlp,
    u8* __restrict__ BT2,
    const float* __restrict__ x, const float* __restrict__ normw,
    u8* __restrict__ xn) {
    __shared__ float t[32][33];
    const int bid = blockIdx.x;
    const int tid = threadIdx.x;
    if (bid < 6912) {
        const float* src; u8* dst; int R, Cc, dstride, doff, bx, by;
        if (bid < 4032) {
            src = Wqkv; dst = WqkvT; R = CDIM; Cc = NPROJ; dstride = CDIM; doff = 0;
            bx = bid % 168; by = bid / 168;
        } else if (bid < 4608) {
            const int b2 = bid - 4032;
            src = Wout; dst = BT2; R = CDIM; Cc = CDIM; dstride = KFF; doff = 0;
            bx = b2 % 24; by = b2 / 24;
        } else {
            const int b2 = bid - 4608;
            src = Wmlp; dst = BT2; R = 3072; Cc = CDIM; dstride = KFF; doff = 768;
            bx = b2 % 24; by = b2 / 24;
        }
        const int c0 = bx * 32, r0 = by * 32;
        const int tx = tid & 31, ty = tid >> 5;
#pragma unroll
        for (int i = 0; i < 32; i += 8) {
            int r = r0 + ty + i, c = c0 + tx;
            if (r < R && c < Cc) t[ty + i][tx] = src[(size_t)r * Cc + c];
        }
        __syncthreads();
#pragma unroll
        for (int i = 0; i < 32; i += 8) {
            int c = c0 + ty + i, r = r0 + tx;
            if (r < R && c < Cc) dst[(size_t)c * dstride + doff + r] = f2fp8(t[tx][ty + i]);
        }
    } else {
        // ---- LayerNorm over C=768, 4 rows/block, one wave per row, fp8 out
        const int row = (bid - 6912) * 4 + (tid >> 6);
        const int lane = tid & 63;
        const f4* xr = (const f4*)(x + (size_t)row * CDIM);
        const f4* wr = (const f4*)normw;
        f4 v[3];
        float s = 0.f, s2 = 0.f;
#pragma unroll
        for (int i = 0; i < 3; ++i) {
            v[i] = xr[lane + 64 * i];
#pragma unroll
            for (int j = 0; j < 4; ++j) { s += v[i][j]; s2 += v[i][j] * v[i][j]; }
        }
        s = wsum64(s); s2 = wsum64(s2);
        float mu = s * (1.f / 768.f);
        float var = s2 * (1.f / 768.f) - mu * mu;
        float rs = rsqrtf(var + 1e-5f);
        u32* xo = (u32*)(xn + (size_t)row * CDIM);
#pragma unroll
        for (int i = 0; i < 3; ++i) {
            f4 wv = wr[lane + 64 * i];
            xo[lane + 64 * i] = pk4_fp8((v[i][0] - mu) * rs * wv[0], (v[i][1] - mu) * rs * wv[1],
                                        (v[i][2] - mu) * rs * wv[2], (v[i][3] - mu) * rs * wv[3]);
        }
    }
}

// ---------------- MX-fp8 MFMA GEMM (unit scales), A (MxK) fp8, B^T (NxK) fp8.
// ROUND-5: reverted VERBATIM to the round-0 proven kernel (122 us, MfmaUtil 23%).
// Structural variants tested and all slower: 256^2 8-phase (240), 64K dbuf
// (156), 32K dbuf BK=64 32x32x64 (133). The 2-barrier 128^2 single-buffer
// loop at ~2.3 blocks/CU wins via implicit inter-block overlap (m114).
// 128x128 block tile, BK=128, 128B LDS rows with 16B-granule XOR swizzle.
// MODE 0: proj epilogue (+bqkv; cols<2304 -> fp8 qkv; else fast-gelu -> fp8 A2 ff)
// MODE 1: final epilogue (+bout+bmlp, out = x + gamma*acc, fp32)
template <int MODE>
__global__ __launch_bounds__(256) void gemm_bt(
    const u8* __restrict__ A, const u8* __restrict__ B, int M, int N, int K,
    const float* __restrict__ bias0, const float* __restrict__ bias1,
    const float* __restrict__ xres, const float* __restrict__ gamma,
    u8* __restrict__ oqkv, u8* __restrict__ off, float* __restrict__ ofin) {
    __shared__ __align__(16) u8 As[128 * 128];
    __shared__ __align__(16) u8 Bs[128 * 128];
    const int tid = threadIdx.x;
    const int wid = tid >> 6, lane = tid & 63;
    const int wm = wid >> 1, wn = wid & 1;
    const int quad = lane >> 4, l16 = lane & 15;
    const int m0 = blockIdx.y * 128, n0 = blockIdx.x * 128;

    f4 acc[4][4] = {};

    // staging: each glds16 call = 8 rows x 128B. 4 A-calls + 4 B-calls per wave.
    const int rl = lane >> 3;
    const int csw = ((lane & 7) ^ rl) * 16;           // swizzled source byte offset
    const u8* aptr[4]; const u8* bptr[4];
    u8* alds[4]; u8* blds[4];
#pragma unroll
    for (int jj = 0; jj < 4; ++jj) {
        const int r0 = wid * 32 + jj * 8;
        aptr[jj] = A + (size_t)(m0 + r0 + rl) * K + csw;
        bptr[jj] = B + (size_t)(n0 + r0 + rl) * K + csw;
        alds[jj] = As + r0 * 128;
        blds[jj] = Bs + r0 * 128;
    }
    const int swl = l16 & 7;                          // read-side swizzle (16B-chunk units)

    for (int kt = 0; kt < K; kt += 128) {
#pragma unroll
        for (int jj = 0; jj < 4; ++jj) {
            gl_lds16(aptr[jj] + kt, alds[jj]);
            gl_lds16(bptr[jj] + kt, blds[jj]);
        }
        __syncthreads();
        const int c0 = ((2 * quad) ^ swl) * 16;
        const int c1 = ((2 * quad + 1) ^ swl) * 16;
        i32x8 af[4], bfv[4];
#pragma unroll
        for (int mi = 0; mi < 4; ++mi) {
            const u8* base = As + (wm * 64 + mi * 16 + l16) * 128;
            uint4 lo = *(const uint4*)(base + c0);
            uint4 hi = *(const uint4*)(base + c1);
            af[mi][0] = lo.x; af[mi][1] = lo.y; af[mi][2] = lo.z; af[mi][3] = lo.w;
            af[mi][4] = hi.x; af[mi][5] = hi.y; af[mi][6] = hi.z; af[mi][7] = hi.w;
        }
#pragma unroll
        for (int ni = 0; ni < 4; ++ni) {
            const u8* base = Bs + (wn * 64 + ni * 16 + l16) * 128;
            uint4 lo = *(const uint4*)(base + c0);
            uint4 hi = *(const uint4*)(base + c1);
            bfv[ni][0] = lo.x; bfv[ni][1] = lo.y; bfv[ni][2] = lo.z; bfv[ni][3] = lo.w;
            bfv[ni][4] = hi.x; bfv[ni][5] = hi.y; bfv[ni][6] = hi.z; bfv[ni][7] = hi.w;
        }
#pragma unroll
        for (int mi = 0; mi < 4; ++mi)
#pragma unroll
            for (int ni = 0; ni < 4; ++ni)
                acc[mi][ni] = __builtin_amdgcn_mfma_scale_f32_16x16x128_f8f6f4(
                    af[mi], bfv[ni], acc[mi][ni], 0, 0, 0, 127, 0, 127);
        __syncthreads();
    }

#pragma unroll
    for (int mi = 0; mi < 4; ++mi) {
#pragma unroll
        for (int ni = 0; ni < 4; ++ni) {
            const int col = n0 + wn * 64 + ni * 16 + l16;
            const int rowb = m0 + wm * 64 + mi * 16 + quad * 4;
            if (MODE == 0) {
                const float bc = bias0[col];
#pragma unroll
                for (int r = 0; r < 4; ++r) {
                    float vv = acc[mi][ni][r] + bc;
                    const int m = rowb + r;
                    if (col < 2304) {
                        oqkv[(size_t)m * 2304 + col] = f2fp8(vv);
                    } else {
                        // fast gelu: x*sigmoid(1.5957691216x + 0.0713548162x^3)
                        float u2 = vv * (-1.5957691216f) - 0.0713548162f * vv * vv * vv;
                        float g = vv / (1.f + __expf(u2));
                        off[(size_t)m * KFF + 768 + (col - 2304)] = f2fp8(g);
                    }
                }
            } else {
                const float bc = bias0[col] + bias1[col];
                const float gm = gamma[col];
#pragma unroll
                for (int r = 0; r < 4; ++r) {
                    const int m = rowb + r;
                    float vv = acc[mi][ni][r] + bc;
                    ofin[(size_t)m * CDIM + col] = xres[(size_t)m * CDIM + col] + gm * vv;
                }
            }
        }
    }
}

// ---------------- fp8 MFMA axial attention: block = (b, line j, head he), 4 waves.
// ROUND-5: qk_ln FUSED into staging. The 4 threads sharing token sr hold the
// full 64-byte head row of q (and k) in registers at load time -> per-head
// LN via 2x shfl_xor over the 4-lane group, then f2fp8 -> LDS. Byte-identical
// to the former standalone qk_ln pass (same fp8->f32->LN->fp8 chain).
// phase 0 = row-j attention, phase 1 = column-j; register-accumulated, one
// fp8 write to A2[tok(b,i,j)]. S^T = K.Q^T (softmax per-lane + 2 quad
// shuffles), P->LDS (u32 packed), O = P.V with V^T built at load.
// All LDS tiles padded to 72B rows -> conflict-free 8B frag reads, no swizzle.
__global__ __launch_bounds__(256) void axial_attn_mfma(const u8* __restrict__ qkv,
                                                       const float* __restrict__ qnw,
                                                       const float* __restrict__ knw,
                                                       u8* __restrict__ A2) {
    __shared__ __align__(16) u8 Qs[64 * 72];
    __shared__ __align__(16) u8 Ks[64 * 72];
    __shared__ __align__(16) u8 Vt[64 * 72];   // V^T[c][k]
    __shared__ __align__(16) u8 Ps[64 * 72];   // P[q][k]

    const int bx = blockIdx.x;
    const int he = bx % 12;
    const int j = (bx / 12) & 63;
    const int b = bx / (12 * 64);
    const int tid = threadIdx.x;
    const int w = tid >> 6, lane = tid & 63;
    const int l16 = lane & 15, quad = lane >> 4;
    const int qb = w * 16;

    f4 acc_o[4] = {};

    // staging thread mapping: row sr = tid>>2 (0..63), 16B segment sc = (tid&3)*16
    const int sr = tid >> 2;
    const int sc = (tid & 3) * 16;
    const f4* qwv = (const f4*)(qnw + sc);
    const f4* kwv = (const f4*)(knw + sc);

    for (int phase = 0; phase < 2; ++phase) {
        const size_t tok = (phase == 0) ? (size_t)((b * 64 + j) * 64 + sr)
                                        : (size_t)((b * 64 + sr) * 64 + j);
        const u8* src = qkv + tok * 2304 + he * 64 + sc;
        // ---- q,k: load + fused per-head LN (4-lane group = one 64-ch head row)
        {
            uint4 qv = *(const uint4*)(src);
            uint4 kv = *(const uint4*)(src + 768);
            const u32* qu = (const u32*)&qv;
            const u32* ku = (const u32*)&kv;
            float qf[16], kf[16];
#pragma unroll
            for (int jj = 0; jj < 4; ++jj)
#pragma unroll
                for (int bb = 0; bb < 4; ++bb) {
                    qf[jj * 4 + bb] = fp8_to_f32((qu[jj] >> (8 * bb)) & 0xffu);
                    kf[jj * 4 + bb] = fp8_to_f32((ku[jj] >> (8 * bb)) & 0xffu);
                }
            float s1q = 0.f, s2q = 0.f, s1k = 0.f, s2k = 0.f;
#pragma unroll
            for (int i = 0; i < 16; ++i) {
                s1q += qf[i]; s2q += qf[i] * qf[i];
                s1k += kf[i]; s2k += kf[i] * kf[i];
            }
            s1q += __shfl_xor(s1q, 1, 64); s1q += __shfl_xor(s1q, 2, 64);
            s2q += __shfl_xor(s2q, 1, 64); s2q += __shfl_xor(s2q, 2, 64);
            s1k += __shfl_xor(s1k, 1, 64); s1k += __shfl_xor(s1k, 2, 64);
            s2k += __shfl_xor(s2k, 1, 64); s2k += __shfl_xor(s2k, 2, 64);
            const float muq = s1q * (1.f / 64.f), muk = s1k * (1.f / 64.f);
            const float rsq = rsqrtf(s2q * (1.f / 64.f) - muq * muq + 1e-5f);
            const float rsk = rsqrtf(s2k * (1.f / 64.f) - muk * muk + 1e-5f);
            uint4 qo, ko;
            u32* qop = (u32*)&qo; u32* kop = (u32*)&ko;
#pragma unroll
            for (int jj = 0; jj < 4; ++jj) {
                const f4 wq = qwv[jj], wk = kwv[jj];
                qop[jj] = pk4_fp8((qf[jj * 4 + 0] - muq) * rsq * wq[0],
                                  (qf[jj * 4 + 1] - muq) * rsq * wq[1],
                                  (qf[jj * 4 + 2] - muq) * rsq * wq[2],
                                  (qf[jj * 4 + 3] - muq) * rsq * wq[3]);
                kop[jj] = pk4_fp8((kf[jj * 4 + 0] - muk) * rsk * wk[0],
                                  (kf[jj * 4 + 1] - muk) * rsk * wk[1],
                                  (kf[jj * 4 + 2] - muk) * rsk * wk[2],
                                  (kf[jj * 4 + 3] - muk) * rsk * wk[3]);
            }
            *(uint4*)(Qs + sr * 72 + sc) = qo;
            *(uint4*)(Ks + sr * 72 + sc) = ko;
        }
        // V transposed: thread owns (k = sr, c in [sc, sc+16))
        {
            uint4 vv = *(const uint4*)(src + 1536);
            const u8* vb = (const u8*)&vv;
#pragma unroll
            for (int i = 0; i < 16; ++i) Vt[(sc + i) * 72 + sr] = vb[i];
        }
        __syncthreads();

        // ---- S^T tiles: D[m=k-idx][n=q], this wave's q-cols = qb..qb+15
        f4 st[4] = {};
#pragma unroll
        for (int kt = 0; kt < 2; ++kt) {
            const int boff = (kt * 4 + quad) * 8;
            const i64 bq = *(const i64*)(Qs + (qb + l16) * 72 + boff);
#pragma unroll
            for (int mt = 0; mt < 4; ++mt) {
                const i64 ak = *(const i64*)(Ks + (mt * 16 + l16) * 72 + boff);
                st[mt] = __builtin_amdgcn_mfma_f32_16x16x32_fp8_fp8(ak, bq, st[mt], 0, 0, 0);
            }
        }

        // ---- softmax over k (= m axis): per-lane 16 values + cross-quad shuffles
        float sv[16];
        float mx = -1e30f;
#pragma unroll
        for (int mt = 0; mt < 4; ++mt)
#pragma unroll
            for (int r = 0; r < 4; ++r) {
                const float s = st[mt][r] * 0.125f;
                sv[mt * 4 + r] = s;
                mx = fmaxf(mx, s);
            }
        mx = fmaxf(mx, __shfl_xor(mx, 16, 64));
        mx = fmaxf(mx, __shfl_xor(mx, 32, 64));
        float sm = 0.f;
#pragma unroll
        for (int i = 0; i < 16; ++i) { sv[i] = __expf(sv[i] - mx); sm += sv[i]; }
        sm += __shfl_xor(sm, 16, 64);
        sm += __shfl_xor(sm, 32, 64);
        const float inv = 1.f / sm;

        // ---- write P[q][k] (transpose out of C-layout), packed u32 stores
#pragma unroll
        for (int mt = 0; mt < 4; ++mt) {
            const int kbase = mt * 16 + quad * 4;
            *(u32*)(Ps + (qb + l16) * 72 + kbase) =
                pk4_fp8(sv[mt * 4] * inv, sv[mt * 4 + 1] * inv,
                        sv[mt * 4 + 2] * inv, sv[mt * 4 + 3] * inv);
        }
        __syncthreads();

        // ---- O += P.V : m-tile = this wave's q rows, n-tiles over c
#pragma unroll
        for (int kt = 0; kt < 2; ++kt) {
            const int boff = (kt * 4 + quad) * 8;
            const i64 ap = *(const i64*)(Ps + (qb + l16) * 72 + boff);
#pragma unroll
            for (int nt = 0; nt < 4; ++nt) {
                const i64 bv = *(const i64*)(Vt + (nt * 16 + l16) * 72 + boff);
                acc_o[nt] = __builtin_amdgcn_mfma_f32_16x16x32_fp8_fp8(ap, bv, acc_o[nt], 0, 0, 0);
            }
        }
        __syncthreads();   // protect tiles before next phase reload
    }

    // ---- store: q = qb + quad*4 + r, c = nt*16 + l16
#pragma unroll
    for (int nt = 0; nt < 4; ++nt)
#pragma unroll
        for (int r = 0; r < 4; ++r) {
            const int q = qb + quad * 4 + r;
            const int c = nt * 16 + l16;
            A2[((size_t)((b * 64 + q) * 64 + j)) * KFF + he * 64 + c] = f2fp8(acc_o[nt][r]);
        }
}

extern "C" void kernel_launch(void* const* d_in, const int* in_sizes, int n_in,
                              void* d_out, int out_size, void* d_ws, size_t ws_size,
                              hipStream_t stream) {
    const float* x = (const float*)d_in[0];
    const float* normw = (const float*)d_in[1];
    const float* Wqkv = (const float*)d_in[2];
    const float* bqkv = (const float*)d_in[3];
    const float* qnw = (const float*)d_in[4];
    const float* knw = (const float*)d_in[5];
    const float* Wout = (const float*)d_in[6];
    const float* bout = (const float*)d_in[7];
    const float* Wmlp = (const float*)d_in[8];
    const float* bmlp = (const float*)d_in[9];
    const float* gamma = (const float*)d_in[10];
    float* out = (float*)d_out;

    char* ws = (char*)d_ws;
    u8* xn = (u8*)ws;    ws += (size_t)NTOK * CDIM;
    u8* WqkvT = (u8*)ws; ws += (size_t)NPROJ * CDIM;
    u8* BT2 = (u8*)ws;   ws += (size_t)CDIM * KFF;
    u8* qkv = (u8*)ws;   ws += (size_t)NTOK * 2304;
    u8* A2 = (u8*)ws;    ws += (size_t)NTOK * KFF;

    // fused prep: weight transposes -> fp8 B^T buffers, plus LN(x) -> fp8
    prep_fused<<<11008, 256, 0, stream>>>(Wqkv, WqkvT, Wout, Wmlp, BT2, x, normw, xn);
    // proj GEMM: q,k,v -> qkv buffer; gelu(ff) -> A2[:, 768:3840]
    gemm_bt<0><<<dim3(NPROJ / 128, NTOK / 128), 256, 0, stream>>>(
        xn, WqkvT, NTOK, NPROJ, CDIM, bqkv, nullptr, nullptr, nullptr, qkv, A2, nullptr);
    // both axial attentions (with fused per-head q/k LN) -> A2[:, 0:768]
    axial_attn_mfma<<<3072, 256, 0, stream>>>(qkv, qnw, knw, A2);
    // final fused GEMM: out = x + gamma * (A2 @ [WoutT|WmlpT] + bout + bmlp)
    gemm_bt<1><<<dim3(CDIM / 128, NTOK / 128), 256, 0, stream>>>(
        A2, BT2, NTOK, CDIM, KFF, bout, bmlp, x, gamma, nullptr, nullptr, out);
}

// Round 6
// 348.889 us; speedup vs baseline: 1.6118x; 1.0546x over previous
//
#include <hip/hip_runtime.h>

typedef unsigned short u16;
typedef unsigned int u32;
typedef unsigned char u8;
typedef long i64;
typedef float f4 __attribute__((ext_vector_type(4)));
typedef int i32x8 __attribute__((ext_vector_type(8)));

#define CDIM 768
#define NPROJ 5376
#define KFF 3840   // combined K for final gemm: 768 (attn) + 3072 (mlp)
#define NTOK 16384

// ---------------- fp8 e4m3 (OCP) conversion helpers, HW cvt when available
__device__ __forceinline__ u8 f2fp8(float f) {
#if __has_builtin(__builtin_amdgcn_cvt_pk_fp8_f32)
    return (u8)(__builtin_amdgcn_cvt_pk_fp8_f32(f, f, 0, false) & 0xff);
#else
    u32 u = __float_as_uint(f);
    u32 s = (u >> 24) & 0x80u;
    float a = fabsf(f);
    a = fminf(a, 448.f);
    if (a < 0.015625f) return (u8)(s | (u32)(a * 512.f + 0.5f));
    u32 b = __float_as_uint(a);
    b += 0x0007FFFFu + ((b >> 20) & 1u);
    u32 e = b >> 23, m = (b >> 20) & 7u;
    u32 code = ((e - 120u) << 3) | m;
    if (code > 0x7Eu) code = 0x7Eu;
    return (u8)(s | code);
#endif
}
__device__ __forceinline__ u32 pk4_fp8(float a, float b, float c, float d) {
#if __has_builtin(__builtin_amdgcn_cvt_pk_fp8_f32)
    u32 lo = (u32)__builtin_amdgcn_cvt_pk_fp8_f32(a, b, 0, false);
    return (u32)__builtin_amdgcn_cvt_pk_fp8_f32(c, d, lo, true);
#else
    return (u32)f2fp8(a) | ((u32)f2fp8(b) << 8) | ((u32)f2fp8(c) << 16) | ((u32)f2fp8(d) << 24);
#endif
}
__device__ __forceinline__ float fp8_to_f32(u32 v) {
#if __has_builtin(__builtin_amdgcn_cvt_f32_fp8)
    return __builtin_amdgcn_cvt_f32_fp8((int)v, 0);
#else
    u32 s = v >> 7, e = (v >> 3) & 15u, m = v & 7u;
    float mag = e ? __uint_as_float(((e + 120u) << 23) | (m << 20))
                  : (float)m * 0.001953125f;
    return s ? -mag : mag;
#endif
}

__device__ __forceinline__ float wsum64(float v) {
#pragma unroll
    for (int m = 32; m > 0; m >>= 1) v += __shfl_xor(v, m, 64);
    return v;
}
__device__ __forceinline__ void gl_lds16(const u8* g, u8* l) {
    __builtin_amdgcn_global_load_lds((__attribute__((address_space(1))) u32*)g,
                                     (__attribute__((address_space(3))) u32*)l,
                                     16, 0, 0);
}

// ---------------- fused prep: 3 weight transpose+casts and the x LayerNorm,
// all independent, in ONE launch (removes 3 launch gaps).
// blocks [0,4032): Wqkv -> WqkvT ; [4032,4608): Wout -> BT2[:,0:768]
// blocks [4608,6912): Wmlp -> BT2[:,768:3840] ; [6912,11008): ln_rows
__global__ __launch_bounds__(256) void prep_fused(
    const float* __restrict__ Wqkv, u8* __restrict__ WqkvT,
    const float* __restrict__ Wout, const float* __restrict__ Wmlp,
    u8* __restrict__ BT2,
    const float* __restrict__ x, const float* __restrict__ normw,
    u8* __restrict__ xn) {
    __shared__ float t[32][33];
    const int bid = blockIdx.x;
    const int tid = threadIdx.x;
    if (bid < 6912) {
        const float* src; u8* dst; int R, Cc, dstride, doff, bx, by;
        if (bid < 4032) {
            src = Wqkv; dst = WqkvT; R = CDIM; Cc = NPROJ; dstride = CDIM; doff = 0;
            bx = bid % 168; by = bid / 168;
        } else if (bid < 4608) {
            const int b2 = bid - 4032;
            src = Wout; dst = BT2; R = CDIM; Cc = CDIM; dstride = KFF; doff = 0;
            bx = b2 % 24; by = b2 / 24;
        } else {
            const int b2 = bid - 4608;
            src = Wmlp; dst = BT2; R = 3072; Cc = CDIM; dstride = KFF; doff = 768;
            bx = b2 % 24; by = b2 / 24;
        }
        const int c0 = bx * 32, r0 = by * 32;
        const int tx = tid & 31, ty = tid >> 5;
#pragma unroll
        for (int i = 0; i < 32; i += 8) {
            int r = r0 + ty + i, c = c0 + tx;
            if (r < R && c < Cc) t[ty + i][tx] = src[(size_t)r * Cc + c];
        }
        __syncthreads();
#pragma unroll
        for (int i = 0; i < 32; i += 8) {
            int c = c0 + ty + i, r = r0 + tx;
            if (r < R && c < Cc) dst[(size_t)c * dstride + doff + r] = f2fp8(t[tx][ty + i]);
        }
    } else {
        // ---- LayerNorm over C=768, 4 rows/block, one wave per row, fp8 out
        const int row = (bid - 6912) * 4 + (tid >> 6);
        const int lane = tid & 63;
        const f4* xr = (const f4*)(x + (size_t)row * CDIM);
        const f4* wr = (const f4*)normw;
        f4 v[3];
        float s = 0.f, s2 = 0.f;
#pragma unroll
        for (int i = 0; i < 3; ++i) {
            v[i] = xr[lane + 64 * i];
#pragma unroll
            for (int j = 0; j < 4; ++j) { s += v[i][j]; s2 += v[i][j] * v[i][j]; }
        }
        s = wsum64(s); s2 = wsum64(s2);
        float mu = s * (1.f / 768.f);
        float var = s2 * (1.f / 768.f) - mu * mu;
        float rs = rsqrtf(var + 1e-5f);
        u32* xo = (u32*)(xn + (size_t)row * CDIM);
#pragma unroll
        for (int i = 0; i < 3; ++i) {
            f4 wv = wr[lane + 64 * i];
            xo[lane + 64 * i] = pk4_fp8((v[i][0] - mu) * rs * wv[0], (v[i][1] - mu) * rs * wv[1],
                                        (v[i][2] - mu) * rs * wv[2], (v[i][3] - mu) * rs * wv[3]);
        }
    }
}

// ---------------- MX-fp8 MFMA GEMM (unit scales), A (MxK) fp8, B^T (NxK) fp8.
// Proven round-0 K-loop (122 us, MfmaUtil 24%) kept UNTOUCHED.
// ROUND-6 additions (epilogue/index only):
//  * bijective XCD swizzle on the linearized grid (nwg%8==0 at both call
//    sites) -> each XCD keeps a contiguous run of m-panels + whole B in L2.
//  * MODE 0: per-head qk LayerNorm FUSED into the epilogue. A wave's cols
//    (n0+wn*64 .. +63) are exactly one 64-ch head; for fixed (mi,r) the row
//    lives in one quad's 16 lanes x 4 ni -> 4 adds + intra-quad shfl_xor
//    (1,2,4,8) give mean/var; normalize with qnw/knw (passed via xres/gamma
//    slots), then f2fp8. LN now on pre-quantization f32 (closer to ref) and
//    computed ONCE per token instead of twice in attn.
// MODE 0: proj epilogue (+bqkv; q,k cols LN'd; v plain; ff fast-gelu -> A2)
// MODE 1: final epilogue (+bout+bmlp, out = x + gamma*acc, fp32)
template <int MODE>
__global__ __launch_bounds__(256) void gemm_bt(
    const u8* __restrict__ A, const u8* __restrict__ B, int M, int N, int K,
    const float* __restrict__ bias0, const float* __restrict__ bias1,
    const float* __restrict__ xres, const float* __restrict__ gamma,
    u8* __restrict__ oqkv, u8* __restrict__ off, float* __restrict__ ofin) {
    __shared__ __align__(16) u8 As[128 * 128];
    __shared__ __align__(16) u8 Bs[128 * 128];
    const int tid = threadIdx.x;
    const int wid = tid >> 6, lane = tid & 63;
    const int wm = wid >> 1, wn = wid & 1;
    const int quad = lane >> 4, l16 = lane & 15;

    // bijective XCD swizzle (both call sites have nwg % 8 == 0)
    const int nbx = (int)gridDim.x;
    const int nwg = (int)(gridDim.x * gridDim.y);
    int bid = (int)(blockIdx.y * gridDim.x + blockIdx.x);
    bid = (bid & 7) * (nwg >> 3) + (bid >> 3);
    const int m0 = (bid / nbx) * 128, n0 = (bid % nbx) * 128;

    f4 acc[4][4] = {};

    // staging: each glds16 call = 8 rows x 128B. 4 A-calls + 4 B-calls per wave.
    const int rl = lane >> 3;
    const int csw = ((lane & 7) ^ rl) * 16;           // swizzled source byte offset
    const u8* aptr[4]; const u8* bptr[4];
    u8* alds[4]; u8* blds[4];
#pragma unroll
    for (int jj = 0; jj < 4; ++jj) {
        const int r0 = wid * 32 + jj * 8;
        aptr[jj] = A + (size_t)(m0 + r0 + rl) * K + csw;
        bptr[jj] = B + (size_t)(n0 + r0 + rl) * K + csw;
        alds[jj] = As + r0 * 128;
        blds[jj] = Bs + r0 * 128;
    }
    const int swl = l16 & 7;                          // read-side swizzle (16B-chunk units)

    for (int kt = 0; kt < K; kt += 128) {
#pragma unroll
        for (int jj = 0; jj < 4; ++jj) {
            gl_lds16(aptr[jj] + kt, alds[jj]);
            gl_lds16(bptr[jj] + kt, blds[jj]);
        }
        __syncthreads();
        const int c0 = ((2 * quad) ^ swl) * 16;
        const int c1 = ((2 * quad + 1) ^ swl) * 16;
        i32x8 af[4], bfv[4];
#pragma unroll
        for (int mi = 0; mi < 4; ++mi) {
            const u8* base = As + (wm * 64 + mi * 16 + l16) * 128;
            uint4 lo = *(const uint4*)(base + c0);
            uint4 hi = *(const uint4*)(base + c1);
            af[mi][0] = lo.x; af[mi][1] = lo.y; af[mi][2] = lo.z; af[mi][3] = lo.w;
            af[mi][4] = hi.x; af[mi][5] = hi.y; af[mi][6] = hi.z; af[mi][7] = hi.w;
        }
#pragma unroll
        for (int ni = 0; ni < 4; ++ni) {
            const u8* base = Bs + (wn * 64 + ni * 16 + l16) * 128;
            uint4 lo = *(const uint4*)(base + c0);
            uint4 hi = *(const uint4*)(base + c1);
            bfv[ni][0] = lo.x; bfv[ni][1] = lo.y; bfv[ni][2] = lo.z; bfv[ni][3] = lo.w;
            bfv[ni][4] = hi.x; bfv[ni][5] = hi.y; bfv[ni][6] = hi.z; bfv[ni][7] = hi.w;
        }
#pragma unroll
        for (int mi = 0; mi < 4; ++mi)
#pragma unroll
            for (int ni = 0; ni < 4; ++ni)
                acc[mi][ni] = __builtin_amdgcn_mfma_scale_f32_16x16x128_f8f6f4(
                    af[mi], bfv[ni], acc[mi][ni], 0, 0, 0, 127, 0, 127);
        __syncthreads();
    }

    const int cbase = n0 + wn * 64;                   // wave's 64-col (one-head) base
#pragma unroll
    for (int mi = 0; mi < 4; ++mi) {
        const int rowb = m0 + wm * 64 + mi * 16 + quad * 4;
        if (MODE == 0) {
            if (cbase < 1536) {
                // ---- q/k: fused per-head LN (wave holds the full 64-ch head row)
                const float* hw = (cbase < 768) ? xres : gamma;   // qnw : knw
                float hwv[4], bc[4];
#pragma unroll
                for (int ni = 0; ni < 4; ++ni) {
                    hwv[ni] = hw[ni * 16 + l16];
                    bc[ni] = bias0[cbase + ni * 16 + l16];
                }
#pragma unroll
                for (int r = 0; r < 4; ++r) {
                    float v[4]; float s1 = 0.f, s2 = 0.f;
#pragma unroll
                    for (int ni = 0; ni < 4; ++ni) {
                        v[ni] = acc[mi][ni][r] + bc[ni];
                        s1 += v[ni]; s2 += v[ni] * v[ni];
                    }
#pragma unroll
                    for (int mk = 1; mk <= 8; mk <<= 1) {
                        s1 += __shfl_xor(s1, mk, 64);
                        s2 += __shfl_xor(s2, mk, 64);
                    }
                    const float mu = s1 * (1.f / 64.f);
                    const float rs = rsqrtf(s2 * (1.f / 64.f) - mu * mu + 1e-5f);
                    const size_t m = (size_t)(rowb + r);
#pragma unroll
                    for (int ni = 0; ni < 4; ++ni)
                        oqkv[m * 2304 + cbase + ni * 16 + l16] =
                            f2fp8((v[ni] - mu) * rs * hwv[ni]);
                }
            } else if (cbase < 2304) {
                // ---- v: plain quantize
#pragma unroll
                for (int ni = 0; ni < 4; ++ni) {
                    const int col = cbase + ni * 16 + l16;
                    const float bcv = bias0[col];
#pragma unroll
                    for (int r = 0; r < 4; ++r)
                        oqkv[(size_t)(rowb + r) * 2304 + col] = f2fp8(acc[mi][ni][r] + bcv);
                }
            } else {
                // ---- ff: fast gelu -> A2
#pragma unroll
                for (int ni = 0; ni < 4; ++ni) {
                    const int col = cbase + ni * 16 + l16;
                    const float bcv = bias0[col];
#pragma unroll
                    for (int r = 0; r < 4; ++r) {
                        float vv = acc[mi][ni][r] + bcv;
                        // fast gelu: x*sigmoid(1.5957691216x + 0.0713548162x^3)
                        float u2 = vv * (-1.5957691216f) - 0.0713548162f * vv * vv * vv;
                        float g = vv / (1.f + __expf(u2));
                        off[(size_t)(rowb + r) * KFF + 768 + (col - 2304)] = f2fp8(g);
                    }
                }
            }
        } else {
#pragma unroll
            for (int ni = 0; ni < 4; ++ni) {
                const int col = cbase + ni * 16 + l16;
                const float bcv = bias0[col] + bias1[col];
                const float gm = gamma[col];
#pragma unroll
                for (int r = 0; r < 4; ++r) {
                    const size_t m = (size_t)(rowb + r);
                    float vv = acc[mi][ni][r] + bcv;
                    ofin[m * CDIM + col] = xres[m * CDIM + col] + gm * vv;
                }
            }
        }
    }
}

// ---------------- fp8 MFMA axial attention: block = (b, line j, head he), 4 waves.
// ROUND-6: LN moved into gemm0 epilogue -> staging reverts to simple loads.
// XCD swizzle on blockIdx (3072 % 8 == 0) for token-row L2 reuse across he.
// phase 0 = row-j attention, phase 1 = column-j; register-accumulated, one
// fp8 write to A2[tok(b,i,j)]. S^T = K.Q^T (softmax per-lane + 2 quad
// shuffles), P->LDS (u32 packed), O = P.V with V^T built at load.
// All LDS tiles padded to 72B rows -> conflict-free 8B frag reads, no swizzle.
__global__ __launch_bounds__(256) void axial_attn_mfma(const u8* __restrict__ qkv,
                                                       u8* __restrict__ A2) {
    __shared__ __align__(16) u8 Qs[64 * 72];
    __shared__ __align__(16) u8 Ks[64 * 72];
    __shared__ __align__(16) u8 Vt[64 * 72];   // V^T[c][k]
    __shared__ __align__(16) u8 Ps[64 * 72];   // P[q][k]

    int bx = (int)blockIdx.x;
    bx = (bx & 7) * 384 + (bx >> 3);           // bijective XCD swizzle (3072/8)
    const int he = bx % 12;
    const int j = (bx / 12) & 63;
    const int b = bx / (12 * 64);
    const int tid = threadIdx.x;
    const int w = tid >> 6, lane = tid & 63;
    const int l16 = lane & 15, quad = lane >> 4;
    const int qb = w * 16;

    f4 acc_o[4] = {};

    // staging thread mapping: row sr = tid>>2 (0..63), 16B segment sc = (tid&3)*16
    const int sr = tid >> 2;
    const int sc = (tid & 3) * 16;

    for (int phase = 0; phase < 2; ++phase) {
        const size_t tok = (phase == 0) ? (size_t)((b * 64 + j) * 64 + sr)
                                        : (size_t)((b * 64 + sr) * 64 + j);
        const u8* src = qkv + tok * 2304 + he * 64 + sc;
        {
            uint4 qv = *(const uint4*)(src);
            uint4 kv = *(const uint4*)(src + 768);
            *(uint4*)(Qs + sr * 72 + sc) = qv;
            *(uint4*)(Ks + sr * 72 + sc) = kv;
        }
        // V transposed: thread owns (k = sr, c in [sc, sc+16))
        {
            uint4 vv = *(const uint4*)(src + 1536);
            const u8* vb = (const u8*)&vv;
#pragma unroll
            for (int i = 0; i < 16; ++i) Vt[(sc + i) * 72 + sr] = vb[i];
        }
        __syncthreads();

        // ---- S^T tiles: D[m=k-idx][n=q], this wave's q-cols = qb..qb+15
        f4 st[4] = {};
#pragma unroll
        for (int kt = 0; kt < 2; ++kt) {
            const int boff = (kt * 4 + quad) * 8;
            const i64 bq = *(const i64*)(Qs + (qb + l16) * 72 + boff);
#pragma unroll
            for (int mt = 0; mt < 4; ++mt) {
                const i64 ak = *(const i64*)(Ks + (mt * 16 + l16) * 72 + boff);
                st[mt] = __builtin_amdgcn_mfma_f32_16x16x32_fp8_fp8(ak, bq, st[mt], 0, 0, 0);
            }
        }

        // ---- softmax over k (= m axis): per-lane 16 values + cross-quad shuffles
        float sv[16];
        float mx = -1e30f;
#pragma unroll
        for (int mt = 0; mt < 4; ++mt)
#pragma unroll
            for (int r = 0; r < 4; ++r) {
                const float s = st[mt][r] * 0.125f;
                sv[mt * 4 + r] = s;
                mx = fmaxf(mx, s);
            }
        mx = fmaxf(mx, __shfl_xor(mx, 16, 64));
        mx = fmaxf(mx, __shfl_xor(mx, 32, 64));
        float sm = 0.f;
#pragma unroll
        for (int i = 0; i < 16; ++i) { sv[i] = __expf(sv[i] - mx); sm += sv[i]; }
        sm += __shfl_xor(sm, 16, 64);
        sm += __shfl_xor(sm, 32, 64);
        const float inv = 1.f / sm;

        // ---- write P[q][k] (transpose out of C-layout), packed u32 stores
#pragma unroll
        for (int mt = 0; mt < 4; ++mt) {
            const int kbase = mt * 16 + quad * 4;
            *(u32*)(Ps + (qb + l16) * 72 + kbase) =
                pk4_fp8(sv[mt * 4] * inv, sv[mt * 4 + 1] * inv,
                        sv[mt * 4 + 2] * inv, sv[mt * 4 + 3] * inv);
        }
        __syncthreads();

        // ---- O += P.V : m-tile = this wave's q rows, n-tiles over c
#pragma unroll
        for (int kt = 0; kt < 2; ++kt) {
            const int boff = (kt * 4 + quad) * 8;
            const i64 ap = *(const i64*)(Ps + (qb + l16) * 72 + boff);
#pragma unroll
            for (int nt = 0; nt < 4; ++nt) {
                const i64 bv = *(const i64*)(Vt + (nt * 16 + l16) * 72 + boff);
                acc_o[nt] = __builtin_amdgcn_mfma_f32_16x16x32_fp8_fp8(ap, bv, acc_o[nt], 0, 0, 0);
            }
        }
        __syncthreads();   // protect tiles before next phase reload
    }

    // ---- store: q = qb + quad*4 + r, c = nt*16 + l16
#pragma unroll
    for (int nt = 0; nt < 4; ++nt)
#pragma unroll
        for (int r = 0; r < 4; ++r) {
            const int q = qb + quad * 4 + r;
            const int c = nt * 16 + l16;
            A2[((size_t)((b * 64 + q) * 64 + j)) * KFF + he * 64 + c] = f2fp8(acc_o[nt][r]);
        }
}

extern "C" void kernel_launch(void* const* d_in, const int* in_sizes, int n_in,
                              void* d_out, int out_size, void* d_ws, size_t ws_size,
                              hipStream_t stream) {
    const float* x = (const float*)d_in[0];
    const float* normw = (const float*)d_in[1];
    const float* Wqkv = (const float*)d_in[2];
    const float* bqkv = (const float*)d_in[3];
    const float* qnw = (const float*)d_in[4];
    const float* knw = (const float*)d_in[5];
    const float* Wout = (const float*)d_in[6];
    const float* bout = (const float*)d_in[7];
    const float* Wmlp = (const float*)d_in[8];
    const float* bmlp = (const float*)d_in[9];
    const float* gamma = (const float*)d_in[10];
    float* out = (float*)d_out;

    char* ws = (char*)d_ws;
    u8* xn = (u8*)ws;    ws += (size_t)NTOK * CDIM;
    u8* WqkvT = (u8*)ws; ws += (size_t)NPROJ * CDIM;
    u8* BT2 = (u8*)ws;   ws += (size_t)CDIM * KFF;
    u8* qkv = (u8*)ws;   ws += (size_t)NTOK * 2304;
    u8* A2 = (u8*)ws;    ws += (size_t)NTOK * KFF;

    // fused prep: weight transposes -> fp8 B^T buffers, plus LN(x) -> fp8
    prep_fused<<<11008, 256, 0, stream>>>(Wqkv, WqkvT, Wout, Wmlp, BT2, x, normw, xn);
    // proj GEMM: q,k (fused per-head LN), v -> qkv buffer; gelu(ff) -> A2[:, 768:3840]
    // (qnw/knw ride in the xres/gamma parameter slots for MODE 0)
    gemm_bt<0><<<dim3(NPROJ / 128, NTOK / 128), 256, 0, stream>>>(
        xn, WqkvT, NTOK, NPROJ, CDIM, bqkv, nullptr, qnw, knw, qkv, A2, nullptr);
    // both axial attentions -> A2[:, 0:768]
    axial_attn_mfma<<<3072, 256, 0, stream>>>(qkv, A2);
    // final fused GEMM: out = x + gamma * (A2 @ [WoutT|WmlpT] + bout + bmlp)
    gemm_bt<1><<<dim3(CDIM / 128, NTOK / 128), 256, 0, stream>>>(
        A2, BT2, NTOK, CDIM, KFF, bout, bmlp, x, gamma, nullptr, nullptr, out);
}